// Round 1
// 590.111 us; speedup vs baseline: 1.1252x; 1.1252x over previous
//
#include <hip/hip_runtime.h>

#define NN 200000
#define NE 3200000
#define NWG 80
static constexpr float EPSV = 1e-5f;

// ---------------- CSR build: 2-level bucket sort ----------------
__global__ void k_cnt_prep(const int* __restrict__ ei, int* __restrict__ bktCnt,
                           const float* __restrict__ x, const float* __restrict__ pos,
                           float4* __restrict__ feat, float* __restrict__ xstats){
  __shared__ int cnt[256];
  __shared__ float sv[256], sq[256];
  int t = threadIdx.x;
  cnt[t] = 0;
  int i = blockIdx.x*256 + t;
  float xf = 0.f;
  if (i < NN){
    xf = x[i];
    feat[i] = make_float4(xf, pos[3*i], pos[3*i+1], 0.f);
  }
  sv[t] = (i < NN) ? xf : 0.f;
  sq[t] = sv[t]*sv[t];
  __syncthreads();
  int tile = blockIdx.x*4096;
  #pragma unroll
  for (int k = 0; k < 16; ++k){
    int e = tile + k*256 + t;
    if (e < NE) atomicAdd(&cnt[ei[NE+e]>>10], 1);
  }
  for (int o = 128; o > 0; o >>= 1){
    __syncthreads();
    if (t < o){ sv[t]+=sv[t+o]; sq[t]+=sq[t+o]; }
  }
  __syncthreads();
  if (t == 0){ atomicAdd(&xstats[0], sv[0]); atomicAdd(&xstats[1], sq[0]); }
  if (cnt[t]) atomicAdd(&bktCnt[t], cnt[t]);
}

__global__ void k_bktscan(const int* __restrict__ bktCnt, int* __restrict__ bktBase,
                          int* __restrict__ bktCur, int* __restrict__ off){
  __shared__ int s[256];
  int t = threadIdx.x;
  int v = bktCnt[t];
  s[t] = v; __syncthreads();
  for (int o = 1; o < 256; o <<= 1){
    int xv = (t >= o) ? s[t-o] : 0;
    __syncthreads(); s[t] += xv; __syncthreads();
  }
  int excl = s[t] - v;
  bktBase[t] = excl;
  bktCur[t]  = excl;
  if (t == 0){ bktBase[256] = NE; off[NN] = NE; }
}

__global__ void k_part1(const int* __restrict__ ei, int* __restrict__ bktCur,
                        int* __restrict__ pairs){
  __shared__ int cnt[256]; __shared__ int base[256]; __shared__ int rank[256];
  int t = threadIdx.x;   // 1024 threads
  if (t < 256) cnt[t] = 0;
  __syncthreads();
  int tile = blockIdx.x*16384;
  #pragma unroll
  for (int k = 0; k < 16; ++k){
    int e = tile + k*1024 + t;
    if (e < NE) atomicAdd(&cnt[ei[NE+e]>>10], 1);
  }
  __syncthreads();
  if (t < 256){
    base[t] = cnt[t] ? atomicAdd(&bktCur[t], cnt[t]) : 0;
    rank[t] = 0;
  }
  __syncthreads();
  #pragma unroll
  for (int k = 0; k < 16; ++k){
    int e = tile + k*1024 + t;
    if (e < NE){
      int d = ei[NE+e], s = ei[e];
      int b = d >> 10;
      int r = atomicAdd(&rank[b], 1);
      pairs[base[b] + r] = (s<<10) | (d & 1023);
    }
  }
}

__global__ void k_part2(const int* __restrict__ pairs, const int* __restrict__ bktBase,
                        int* __restrict__ off, int* __restrict__ srcs){
  __shared__ int hist[1024]; __shared__ int cur[1024];
  int b = blockIdx.x, t = threadIdx.x;
  int p0 = bktBase[b], p1 = bktBase[b+1];
  int cntB = p1 - p0;
  int dstBase = b << 10;
  int width = min(1024, NN - dstBase);
  hist[t] = 0; __syncthreads();
  for (int i = t; i < cntB; i += 1024) atomicAdd(&hist[pairs[p0+i] & 1023], 1);
  __syncthreads();
  int h0 = hist[t];
  for (int o = 1; o < 1024; o <<= 1){
    int xv = (t >= o) ? hist[t-o] : 0;
    __syncthreads(); hist[t] += xv; __syncthreads();
  }
  int excl = hist[t] - h0;
  if (t < width) off[dstBase + t] = p0 + excl;
  cur[t] = excl; __syncthreads();
  for (int i = t; i < cntB; i += 1024){
    int v = pairs[p0+i];
    int r = atomicAdd(&cur[v & 1023], 1);
    srcs[p0 + r] = v >> 10;
  }
}

// ---------------- Block 1 (N=200000, C=16) ----------------
__global__ void k_agg1(const float4* __restrict__ feat, const int* __restrict__ srcs,
                       const int* __restrict__ off, const float* __restrict__ pos,
                       const float* __restrict__ w48, const float* __restrict__ bias,
                       float4* __restrict__ H4){
  int t = threadIdx.x;
  int eidx = t & 15;
  int d = blockIdx.x*16 + (t >> 4);
  int s0 = off[d], s1 = off[d+1];
  float NI = -__builtin_inff();
  float m[16];
  #pragma unroll
  for (int c = 0; c < 16; ++c) m[c] = NI;
  for (int j = s0 + eidx; j < s1; j += 16){
    float4 f = feat[srcs[j]];
    #pragma unroll
    for (int c = 0; c < 16; ++c)
      m[c] = fmaxf(m[c], f.x*w48[c] + f.y*w48[16+c] + f.z*w48[32+c]);
  }
  #pragma unroll
  for (int mask = 1; mask < 16; mask <<= 1){
    #pragma unroll
    for (int c = 0; c < 16; ++c) m[c] = fmaxf(m[c], __shfl_xor(m[c], mask, 64));
  }
  if (eidx == 0){
    float o[16];
    if (s1 > s0){
      float px = pos[3*d], py = pos[3*d+1];
      #pragma unroll
      for (int c = 0; c < 16; ++c) o[c] = m[c] + bias[c] - (px*w48[16+c] + py*w48[32+c]);
    } else {
      #pragma unroll
      for (int c = 0; c < 16; ++c) o[c] = 0.f;
    }
    H4[d*4+0] = make_float4(o[0],o[1],o[2],o[3]);
    H4[d*4+1] = make_float4(o[4],o[5],o[6],o[7]);
    H4[d*4+2] = make_float4(o[8],o[9],o[10],o[11]);
    H4[d*4+3] = make_float4(o[12],o[13],o[14],o[15]);
  }
}

__global__ void k_agg16w(const float4* __restrict__ A4, const int* __restrict__ srcs,
                         const int* __restrict__ off, const float* __restrict__ pos,
                         const float* __restrict__ wpos, const float* __restrict__ bias,
                         float4* __restrict__ H4){
  int t = threadIdx.x;
  int lane = t & 63;
  int d = blockIdx.x*4 + (t >> 6);
  int eidx = lane >> 2;
  int cg = lane & 3;
  int s0 = off[d], s1 = off[d+1];
  float NI = -__builtin_inff();
  float4 m = make_float4(NI, NI, NI, NI);
  for (int j = s0 + eidx; j < s1; j += 16){
    int s = srcs[j];
    float4 a = A4[s*4 + cg];
    m.x = fmaxf(m.x, a.x); m.y = fmaxf(m.y, a.y);
    m.z = fmaxf(m.z, a.z); m.w = fmaxf(m.w, a.w);
  }
  #pragma unroll
  for (int mask = 4; mask <= 32; mask <<= 1){
    m.x = fmaxf(m.x, __shfl_xor(m.x, mask, 64));
    m.y = fmaxf(m.y, __shfl_xor(m.y, mask, 64));
    m.z = fmaxf(m.z, __shfl_xor(m.z, mask, 64));
    m.w = fmaxf(m.w, __shfl_xor(m.w, mask, 64));
  }
  if (eidx == 0){
    float4 val = make_float4(0.f, 0.f, 0.f, 0.f);
    if (s1 > s0){
      float px = pos[3*d], py = pos[3*d+1];
      int c0 = cg*4;
      val.x = m.x + bias[c0+0] - (px*wpos[c0+0] + py*wpos[16+c0+0]);
      val.y = m.y + bias[c0+1] - (px*wpos[c0+1] + py*wpos[16+c0+1]);
      val.z = m.z + bias[c0+2] - (px*wpos[c0+2] + py*wpos[16+c0+2]);
      val.w = m.w + bias[c0+3] - (px*wpos[c0+3] + py*wpos[16+c0+3]);
    }
    H4[d*4 + cg] = val;
  }
}

__global__ void k_stats16(const float* __restrict__ H, float* __restrict__ st){
  int t = threadIdx.x;
  float s = 0.f, q = 0.f;
  for (int idx = blockIdx.x*256 + t; idx < NN*16; idx += gridDim.x*256){
    float v = H[idx]; s += v; q += v*v;
  }
  __shared__ float sv[256], sq[256];
  sv[t] = s; sq[t] = q; __syncthreads();
  for (int o = 128; o >= 16; o >>= 1){
    if (t < o){ sv[t]+=sv[t+o]; sq[t]+=sq[t+o]; } __syncthreads();
  }
  if (t < 16){ atomicAdd(&st[t], sv[t]); atomicAdd(&st[16+t], sq[t]); }
}

__global__ void k_prep2(const float* __restrict__ Hraw, const float* __restrict__ st1,
                        const float* __restrict__ pos, const float* __restrict__ w,
                        float4* __restrict__ A4){
  int idx = blockIdx.x*blockDim.x + threadIdx.x;
  if (idx >= NN*4) return;
  int i = idx >> 2, cg = idx & 3;
  const float inv_n = 1.f/(float)NN;
  float acc0 = 0.f, acc1 = 0.f, acc2 = 0.f, acc3 = 0.f;
  #pragma unroll
  for (int k = 0; k < 16; ++k){
    float mk = st1[k]*inv_n;
    float vk = st1[16+k]*inv_n - mk*mk;
    float ik = rsqrtf(vk + EPSV);
    float h = fmaxf((Hraw[i*16+k]-mk)*ik, 0.f);
    acc0 += h*w[k*16 + cg*4 + 0];
    acc1 += h*w[k*16 + cg*4 + 1];
    acc2 += h*w[k*16 + cg*4 + 2];
    acc3 += h*w[k*16 + cg*4 + 3];
  }
  float px = pos[3*i], py = pos[3*i+1];
  int c0 = cg*4;
  acc0 += px*w[256+c0+0] + py*w[272+c0+0];
  acc1 += px*w[256+c0+1] + py*w[272+c0+1];
  acc2 += px*w[256+c0+2] + py*w[272+c0+2];
  acc3 += px*w[256+c0+3] + py*w[272+c0+3];
  A4[idx] = make_float4(acc0, acc1, acc2, acc3);
}

__global__ void k_comb_pool(const float* __restrict__ H, const float* __restrict__ x,
                            const float* __restrict__ pos, const float* __restrict__ lw,
                            const float* __restrict__ st2, const float* __restrict__ xstats,
                            float* __restrict__ mem){
  int idx = blockIdx.x*blockDim.x + threadIdx.x;
  if (idx >= NN*4) return;
  int i = idx >> 2, cg = idx & 3;
  const float inv_n = 1.f/(float)NN;
  float mx = xstats[0]*inv_n, vx = xstats[1]*inv_n - mx*mx;
  float xc = x[i] - mx;
  float px = pos[3*i], py = pos[3*i+1];
  int cx = (int)(px * 80.f / 240.f); cx = min(max(cx,0),79);
  int cy = (int)(py * 60.f / 180.f); cy = min(max(cy,0),59);
  float* mrow = &mem[(cy*80+cx)*16 + cg*4];
  #pragma unroll
  for (int k = 0; k < 4; ++k){
    int c = cg*4 + k;
    float m2 = st2[c]*inv_n, v2 = st2[16+c]*inv_n - m2*m2;
    float i2 = rsqrtf(v2 + EPSV);
    float a = lw[c];
    float sc = a * rsqrtf(a*a*vx + EPSV);
    float v = (H[i*16+c]-m2)*i2 + xc*sc;
    v = fmaxf(v, 0.f);
    atomicAdd(&mrow[k], v);
  }
}

// ---------------- Fused tail: halo-tiled, LDS-resident, 8 grid barriers ----------------
__device__ __forceinline__ void stwt(float* p, float v){
  __hip_atomic_store(p, v, __ATOMIC_RELAXED, __HIP_MEMORY_SCOPE_AGENT);
}
__device__ __forceinline__ float ldwt(const float* p){
  return __hip_atomic_load(p, __ATOMIC_RELAXED, __HIP_MEMORY_SCOPE_AGENT);
}

// bar layout (ints, zeroed each launch): [0..255] 8 slots stride 32; [256] master; [288] generation
__device__ __forceinline__ void gridbar(int* bar){
  __syncthreads();
  if (threadIdx.x == 0){
    __atomic_signal_fence(__ATOMIC_SEQ_CST);
    __builtin_amdgcn_s_waitcnt(0);   // all write-through stores durable at coherent point
    __atomic_signal_fence(__ATOMIC_SEQ_CST);
    int g = __hip_atomic_load(bar+288, __ATOMIC_RELAXED, __HIP_MEMORY_SCOPE_AGENT);
    int slot = blockIdx.x & 7;
    int a = __hip_atomic_fetch_add(bar + slot*32, 1, __ATOMIC_RELAXED, __HIP_MEMORY_SCOPE_AGENT);
    bool released = false;
    if (a == (NWG/8 - 1)){
      int m = __hip_atomic_fetch_add(bar + 256, 1, __ATOMIC_RELAXED, __HIP_MEMORY_SCOPE_AGENT);
      if (m == 7){
        #pragma unroll
        for (int s = 0; s < 8; ++s)
          __hip_atomic_store(bar + s*32, 0, __ATOMIC_RELAXED, __HIP_MEMORY_SCOPE_AGENT);
        __hip_atomic_store(bar + 256, 0, __ATOMIC_RELAXED, __HIP_MEMORY_SCOPE_AGENT);
        __atomic_signal_fence(__ATOMIC_SEQ_CST);
        __builtin_amdgcn_s_waitcnt(0);   // zeroing durable BEFORE generation bump
        __atomic_signal_fence(__ATOMIC_SEQ_CST);
        __hip_atomic_fetch_add(bar + 288, 1, __ATOMIC_RELAXED, __HIP_MEMORY_SCOPE_AGENT);
        released = true;
      }
    }
    if (!released){
      while (__hip_atomic_load(bar+288, __ATOMIC_RELAXED, __HIP_MEMORY_SCOPE_AGENT) == g)
        __builtin_amdgcn_s_sleep(2);
    }
  }
  __syncthreads();
}

struct TailP {
  const float *mem1;
  const float *p1w,*p1b,*p2w,*p2b,*p3w,*p3b;
  const float *c1w2,*c1b2,*c2w2,*c2b2,*lw2,*lb2;
  const float *c1w3,*c1b3,*c2w3,*c2b3,*lw3,*lb3;
  const float *c1w4,*c1b4,*c2w4,*c2b4,*lw4,*lb4;
  float *g2p,*g3p;
  float *stB2sk,*stB2c1,*stB2c2,*stB3sk,*stB3c1,*stB3c2,*stB4sk,*stB4c1,*stB4c2;
  float *out;
  int *bar;
};

// Phase A: G on T+2 halo (poollin for block2, ldwt(Gp) else); S = G@c1w on T+2;
//          SK = G@lw+lb on T (+stats); H1 = gridagg(S) on T+1 (+stats over owned T).
template<int GW,int GH,int TW,int TH,int K,int C,bool FIRST>
__device__ __forceinline__ void ph_A(float* buf, float* sv, float* sq,
    const float* __restrict__ Gglob, const float* __restrict__ plw, const float* __restrict__ plb,
    const float* __restrict__ c1w, const float* __restrict__ c1b,
    const float* __restrict__ lw, const float* __restrict__ lb,
    float* stH1, float* stSK, float sx, float sy, int tile)
{
  constexpr int W2=TW+4, nR2=W2*(TH+4);
  constexpr int W1=TW+2, nR1=W1*(TH+2);
  constexpr int nT=TW*TH, NTX=GW/TW;
  const int tx0=(tile%NTX)*TW, ty0=(tile/NTX)*TH;
  float* Gl=buf; float* Sl=Gl+nR2*K; float* H1l=Sl+nR2*C; float* SKl=H1l+nR1*C;
  const int t=threadIdx.x;
  if constexpr (FIRST){
    for (int e=t; e<nR2*K; e+=256){
      int cell=e/K, k=e-cell*K;
      int gx=tx0-2+cell%W2, gy=ty0-2+cell/W2;
      Sl[e] = (gx>=0&&gx<GW&&gy>=0&&gy<GH) ? Gglob[(gy*GW+gx)*K+k] : 0.f;
    }
    __syncthreads();
    for (int e=t; e<nR2*K; e+=256){
      int cell=e/K, c=e-cell*K;
      float acc=plb[c];
      #pragma unroll
      for (int k=0;k<K;++k) acc += Sl[cell*K+k]*plw[k*K+c];
      Gl[e] = (acc>1.f)?acc:0.f;
    }
  } else {
    for (int e=t; e<nR2*K; e+=256){
      int cell=e/K, k=e-cell*K;
      int gx=tx0-2+cell%W2, gy=ty0-2+cell/W2;
      Gl[e] = (gx>=0&&gx<GW&&gy>=0&&gy<GH) ? ldwt(&Gglob[(gy*GW+gx)*K+k]) : 0.f;
    }
  }
  __syncthreads();
  // S on T+2 (out-of-grid cells compute from zeros; never read)
  for (int e=t; e<nR2*C; e+=256){
    int cell=e/C, c=e-cell*C;
    float acc=0.f;
    #pragma unroll 8
    for (int k=0;k<K;++k) acc += Gl[cell*K+k]*c1w[k*C+c];
    Sl[e]=acc;
  }
  // SK on owned T + stats
  float ls=0.f,lq=0.f;
  for (int e=t; e<nT*C; e+=256){
    int cell=e/C, c=e-cell*C;
    int lx=cell%TW, ly=cell/TW;
    int g2=(ly+2)*W2+(lx+2);
    float acc=lb[c];
    #pragma unroll 8
    for (int k=0;k<K;++k) acc += Gl[g2*K+k]*lw[k*C+c];
    SKl[e]=acc; ls+=acc; lq+=acc*acc;
  }
  __syncthreads();
  sv[t]=ls; sq[t]=lq; __syncthreads();
  for (int o=128;o>=C;o>>=1){ if(t<o){sv[t]+=sv[t+o];sq[t]+=sq[t+o];} __syncthreads(); }
  if (t<C){ atomicAdd(&stSK[t],sv[t]); atomicAdd(&stSK[C+t],sq[t]); }
  __syncthreads();
  // H1 = gridagg(S) on T+1; stats over owned T only
  ls=0.f; lq=0.f;
  const float NI=-__builtin_inff();
  for (int e=t; e<nR1*C; e+=256){
    int cell=e/C, c=e-cell*C;
    int lx=cell%W1, ly=cell/W1;
    int gx=tx0-1+lx, gy=ty0-1+ly;
    if (gx<0||gx>=GW||gy<0||gy>=GH) continue;
    float wx=c1w[K*C+c], wy=c1w[(K+1)*C+c];
    float m=NI;
    #pragma unroll
    for (int oy=-1;oy<=1;++oy){
      int ny=gy+oy; if (ny<0||ny>=GH) continue;
      #pragma unroll
      for (int ox=-1;ox<=1;++ox){
        int nx=gx+ox; if (nx<0||nx>=GW) continue;
        int l2=(ly+1+oy)*W2+(lx+1+ox);
        m=fmaxf(m, Sl[l2*C+c]+(ox*sx)*wx+(oy*sy)*wy);
      }
    }
    float val=m+c1b[c];
    H1l[e]=val;
    if (gx>=tx0&&gx<tx0+TW&&gy>=ty0&&gy<ty0+TH){ ls+=val; lq+=val*val; }
  }
  __syncthreads();
  sv[t]=ls; sq[t]=lq; __syncthreads();
  for (int o=128;o>=C;o>>=1){ if(t<o){sv[t]+=sv[t+o];sq[t]+=sq[t+o];} __syncthreads(); }
  if (t<C){ atomicAdd(&stH1[t],sv[t]); atomicAdd(&stH1[C+t],sq[t]); }
}

// Phase B: normalize H1 (global stats) on T+1; S2 = relu(BN(H1))@c2w on T+1;
//          H2 = gridagg(S2) on T (+stats).
template<int GW,int GH,int TW,int TH,int K,int C>
__device__ __forceinline__ void ph_B(float* buf, float* sv, float* sq, float* la, float* lbv,
    const float* __restrict__ c2w, const float* __restrict__ c2b,
    const float* stH1, float* stH2, float sx, float sy, int tile)
{
  constexpr int W2=TW+4, nR2=W2*(TH+4);
  constexpr int W1=TW+2, nR1=W1*(TH+2);
  constexpr int nT=TW*TH, NTX=GW/TW;
  const int tx0=(tile%NTX)*TW, ty0=(tile/NTX)*TH;
  float* Gl=buf; float* Sl=Gl+nR2*K; float* H1l=Sl+nR2*C; float* SKl=H1l+nR1*C; float* H2l=SKl+nT*C;
  const int t=threadIdx.x;
  const float invn=1.f/(float)(GW*GH);
  if (t<C){
    float mk=ldwt(&stH1[t])*invn;
    float vk=ldwt(&stH1[C+t])*invn - mk*mk;
    float ik=rsqrtf(vk+EPSV);
    la[t]=ik; lbv[t]=-mk*ik;
  }
  __syncthreads();
  for (int e=t;e<nR1*C;e+=256){
    int cell=e/C,c=e-cell*C;
    int gx=tx0-1+cell%W1, gy=ty0-1+cell/W1;
    if (gx<0||gx>=GW||gy<0||gy>=GH) continue;
    H1l[e]=fmaxf(H1l[e]*la[c]+lbv[c],0.f);
  }
  __syncthreads();
  // S2 on T+1 (region1 layout, reusing S buffer)
  for (int e=t;e<nR1*C;e+=256){
    int cell=e/C,c=e-cell*C;
    int gx=tx0-1+cell%W1, gy=ty0-1+cell/W1;
    if (gx<0||gx>=GW||gy<0||gy>=GH) continue;
    float acc=0.f;
    #pragma unroll 8
    for (int k=0;k<C;++k) acc += H1l[cell*C+k]*c2w[k*C+c];
    Sl[e]=acc;
  }
  __syncthreads();
  float ls=0.f,lq=0.f;
  const float NI=-__builtin_inff();
  for (int e=t;e<nT*C;e+=256){
    int cell=e/C,c=e-cell*C;
    int lx=cell%TW, ly=cell/TW;
    int gx=tx0+lx, gy=ty0+ly;
    float wx=c2w[C*C+c], wy=c2w[(C+1)*C+c];
    float m=NI;
    #pragma unroll
    for (int oy=-1;oy<=1;++oy){
      int ny=gy+oy; if (ny<0||ny>=GH) continue;
      #pragma unroll
      for (int ox=-1;ox<=1;++ox){
        int nx=gx+ox; if (nx<0||nx>=GW) continue;
        int l1=(ly+1+oy)*W1+(lx+1+ox);
        m=fmaxf(m, Sl[l1*C+c]+(ox*sx)*wx+(oy*sy)*wy);
      }
    }
    float val=m+c2b[c];
    H2l[e]=val; ls+=val; lq+=val*val;
  }
  __syncthreads();
  sv[t]=ls; sq[t]=lq; __syncthreads();
  for (int o=128;o>=C;o>>=1){ if(t<o){sv[t]+=sv[t+o];sq[t]+=sq[t+o];} __syncthreads(); }
  if (t<C){ atomicAdd(&stH2[t],sv[t]); atomicAdd(&stH2[C+t],sq[t]); }
}

// Phase C: out = relu(BN(H2)+BN(SK)) on T -> global; 2x2 pool + poollin -> Gp.
template<int GW,int GH,int TW,int TH,int K,int C,bool POOL>
__device__ __forceinline__ void ph_C(float* buf, float* asv, float* asq, float* la, float* lbv,
    const float* stH2, const float* stSK,
    const float* __restrict__ pw, const float* __restrict__ pb,
    float* __restrict__ outg, float* __restrict__ Gpg, int tile)
{
  constexpr int W2=TW+4, nR2=W2*(TH+4);
  constexpr int W1=TW+2, nR1=W1*(TH+2);
  constexpr int nT=TW*TH, NTX=GW/TW;
  const int tx0=(tile%NTX)*TW, ty0=(tile/NTX)*TH;
  float* Gl=buf; float* Sl=Gl+nR2*K; float* H1l=Sl+nR2*C; float* SKl=H1l+nR1*C; float* H2l=SKl+nT*C;
  const int t=threadIdx.x;
  const float invn=1.f/(float)(GW*GH);
  if (t<C){
    float m2=ldwt(&stH2[t])*invn, v2=ldwt(&stH2[C+t])*invn-m2*m2;
    float i2=rsqrtf(v2+EPSV);
    la[t]=i2; lbv[t]=-m2*i2;
    float ms=ldwt(&stSK[t])*invn, vs=ldwt(&stSK[C+t])*invn-ms*ms;
    float is_=rsqrtf(vs+EPSV);
    asv[t]=is_; asq[t]=-ms*is_;
  }
  __syncthreads();
  float* OUTl=Sl;   // S2 dead; reuse as combined-output tile
  for (int e=t;e<nT*C;e+=256){
    int cell=e/C,c=e-cell*C;
    int lx=cell%TW, ly=cell/TW;
    int gx=tx0+lx, gy=ty0+ly;
    float v=(H2l[e]*la[c]+lbv[c])+(SKl[e]*asv[c]+asq[c]);
    v=fmaxf(v,0.f);
    outg[(gy*GW+gx)*C+c]=v;   // plain store: flushed at kernel end
    OUTl[e]=v;
  }
  if constexpr (POOL){
    __syncthreads();
    constexpr int PTW=TW/2, PTH=TH/2, nP=PTW*PTH, PGW=GW/2;
    float* Ml=H1l;  // H1 dead; reuse as pooled sums
    for (int e=t;e<nP*C;e+=256){
      int pc=e/C,c=e-pc*C;
      int plx=pc%PTW, ply=pc/PTW;
      float s=0.f;
      #pragma unroll
      for (int dy=0;dy<2;++dy)
        #pragma unroll
        for (int dx=0;dx<2;++dx)
          s += OUTl[((2*ply+dy)*TW+(2*plx+dx))*C+c];
      Ml[e]=s;
    }
    __syncthreads();
    for (int e=t;e<nP*C;e+=256){
      int pc=e/C,c=e-pc*C;
      int plx=pc%PTW, ply=pc/PTW;
      float acc=pb[c];
      #pragma unroll 8
      for (int k=0;k<C;++k) acc += Ml[pc*C+k]*pw[k*C+c];
      int gpx=tx0/2+plx, gpy=ty0/2+ply;
      stwt(&Gpg[(gpy*PGW+gpx)*C+c], (acc>1.f)?acc:0.f);
    }
  }
  (void)nR1;
}

__global__ void __launch_bounds__(256) k_tail(TailP P){
  __shared__ float sv[256], sq[256], la[128], lbv[128];
  __shared__ float buf[13824];   // 55.3 KB union of per-block halo tiles
  int* bar = P.bar;
  const int tile = blockIdx.x;

  // ---- block 2 (80x60, 16->32), tile 10x6, 80 tiles ----
  if (tile < 80) ph_A<80,60,10,6,16,32,true >(buf,sv,sq,P.mem1,P.p1w,P.p1b,P.c1w2,P.c1b2,P.lw2,P.lb2,P.stB2c1,P.stB2sk,3.f,3.f,tile);
  gridbar(bar);
  if (tile < 80) ph_B<80,60,10,6,16,32>(buf,sv,sq,la,lbv,P.c2w2,P.c2b2,P.stB2c1,P.stB2c2,3.f,3.f,tile);
  gridbar(bar);
  if (tile < 80) ph_C<80,60,10,6,16,32,true >(buf,sv,sq,la,lbv,P.stB2c2,P.stB2sk,P.p2w,P.p2b,P.out,P.g2p,tile);
  gridbar(bar);
  // ---- block 3 (40x30, 32->64), tile 4x6, 50 tiles ----
  if (tile < 50) ph_A<40,30,4,6,32,64,false>(buf,sv,sq,P.g2p,nullptr,nullptr,P.c1w3,P.c1b3,P.lw3,P.lb3,P.stB3c1,P.stB3sk,6.f,6.f,tile);
  gridbar(bar);
  if (tile < 50) ph_B<40,30,4,6,32,64>(buf,sv,sq,la,lbv,P.c2w3,P.c2b3,P.stB3c1,P.stB3c2,6.f,6.f,tile);
  gridbar(bar);
  if (tile < 50) ph_C<40,30,4,6,32,64,true >(buf,sv,sq,la,lbv,P.stB3c2,P.stB3sk,P.p3w,P.p3b,P.out+153600,P.g3p,tile);
  gridbar(bar);
  // ---- block 4 (20x15, 64->128), tile 2x3, 50 tiles, no pool ----
  if (tile < 50) ph_A<20,15,2,3,64,128,false>(buf,sv,sq,P.g3p,nullptr,nullptr,P.c1w4,P.c1b4,P.lw4,P.lb4,P.stB4c1,P.stB4sk,12.f,12.f,tile);
  gridbar(bar);
  if (tile < 50) ph_B<20,15,2,3,64,128>(buf,sv,sq,la,lbv,P.c2w4,P.c2b4,P.stB4c1,P.stB4c2,12.f,12.f,tile);
  gridbar(bar);
  if (tile < 50) ph_C<20,15,2,3,64,128,false>(buf,sv,sq,la,lbv,P.stB4c2,P.stB4sk,nullptr,nullptr,P.out+230400,nullptr,tile);
}

extern "C" void kernel_launch(void* const* d_in, const int* in_sizes, int n_in,
                              void* d_out, int out_size, void* d_ws, size_t ws_size,
                              hipStream_t stream){
  const float* x   = (const float*)d_in[0];
  const float* pos = (const float*)d_in[1];
  const int*   ei  = (const int*)d_in[2];
  const float* b1_c1w = (const float*)d_in[3];
  const float* b1_c1b = (const float*)d_in[4];
  const float* b1_c2w = (const float*)d_in[5];
  const float* b1_lw  = (const float*)d_in[7];
  const float* b1_c2b = (const float*)d_in[6];
  const float* b2_c1w = (const float*)d_in[9];
  const float* b2_c1b = (const float*)d_in[10];
  const float* b2_c2w = (const float*)d_in[11];
  const float* b2_c2b = (const float*)d_in[12];
  const float* b2_lw  = (const float*)d_in[13];
  const float* b2_lb  = (const float*)d_in[14];
  const float* b3_c1w = (const float*)d_in[15];
  const float* b3_c1b = (const float*)d_in[16];
  const float* b3_c2w = (const float*)d_in[17];
  const float* b3_c2b = (const float*)d_in[18];
  const float* b3_lw  = (const float*)d_in[19];
  const float* b3_lb  = (const float*)d_in[20];
  const float* b4_c1w = (const float*)d_in[21];
  const float* b4_c1b = (const float*)d_in[22];
  const float* b4_c2w = (const float*)d_in[23];
  const float* b4_c2b = (const float*)d_in[24];
  const float* b4_lw  = (const float*)d_in[25];
  const float* b4_lb  = (const float*)d_in[26];
  const float* p1w = (const float*)d_in[27];
  const float* p1b = (const float*)d_in[28];
  const float* p2w = (const float*)d_in[29];
  const float* p2b = (const float*)d_in[30];
  const float* p3w = (const float*)d_in[31];
  const float* p3b = (const float*)d_in[32];
  float* out = (float*)d_out;

  // ---- workspace carve ----
  float4* feat = (float4*)d_ws;       // NN float4 (3.2MB)
  float* A  = (float*)(feat + NN);    // NN*16 fp32; pairs + inter-block buffers ALIAS (A dead then)
  int* pairs = (int*)A;               // NE ints — ALIAS
  float* g2p  = A;                    // 1200*32 — alias, A dead after k_agg16w/k_comb_pool
  float* g3p  = A + 38400;            // 300*64
  float* H  = A + NN*16;              // NN*16
  // Z region (single memset): bucket counters, barrier, stats, mem1
  int* bktCnt  = (int*)(H + NN*16);   // 256
  int* bktBase = bktCnt + 256;        // 257
  int* bktCur  = bktBase + 257;       // ends 769, pad to 1024
  int* bar     = bktCnt + 1024;       // 320 (pad to 2048)
  float* STz   = (float*)(bktCnt + 2048);
  float* xstats = STz;                // 2
  float* st1    = STz + 16;
  float* st2    = STz + 64;
  float* stB2sk = STz + 128;
  float* stB2c1 = STz + 192;
  float* stB2c2 = STz + 256;
  float* stB3sk = STz + 320;
  float* stB3c1 = STz + 448;
  float* stB3c2 = STz + 576;
  float* stB4sk = STz + 704;
  float* stB4c1 = STz + 960;
  float* stB4c2 = STz + 1216;         // ..1471, pad to 1536
  float* mem1   = STz + 1536;         // 76800
  const size_t ZBYTES = (size_t)(2048 + 1536 + 76800) * 4;
  int* off    = (int*)(mem1 + 76800); // NN+1
  int* srcs   = off + (NN+1);         // NE

  hipMemsetAsync(bktCnt, 0, ZBYTES, stream);

  const int B = 256;
  // CSR build (fused with feat/xstats prep)
  k_cnt_prep<<<(NE+4095)/4096, 256, 0, stream>>>(ei, bktCnt, x, pos, feat, xstats);
  k_bktscan <<<1, 256, 0, stream>>>(bktCnt, bktBase, bktCur, off);
  k_part1   <<<(NE+16383)/16384, 1024, 0, stream>>>(ei, bktCur, pairs);
  k_part2   <<<196, 1024, 0, stream>>>(pairs, bktBase, off, srcs);

  // Block 1
  k_agg1    <<<NN/16, B, 0, stream>>>(feat, srcs, off, pos, b1_c1w, b1_c1b, (float4*)H);
  k_stats16 <<<256, B, 0, stream>>>(H, st1);
  k_prep2   <<<(NN*4+B-1)/B, B, 0, stream>>>(H, st1, pos, b1_c2w, (float4*)A);
  k_agg16w  <<<NN/4, B, 0, stream>>>((const float4*)A, srcs, off, pos, b1_c2w+256, b1_c2b, (float4*)H);
  k_stats16 <<<256, B, 0, stream>>>(H, st2);
  k_comb_pool<<<(NN*4+B-1)/B, B, 0, stream>>>(H, x, pos, b1_lw, st2, xstats, mem1);

  // Fused tail: halo-tiled LDS-resident blocks 2-4, 8 grid barriers
  TailP P;
  P.mem1 = mem1;
  P.p1w = p1w; P.p1b = p1b; P.p2w = p2w; P.p2b = p2b; P.p3w = p3w; P.p3b = p3b;
  P.c1w2 = b2_c1w; P.c1b2 = b2_c1b; P.c2w2 = b2_c2w; P.c2b2 = b2_c2b; P.lw2 = b2_lw; P.lb2 = b2_lb;
  P.c1w3 = b3_c1w; P.c1b3 = b3_c1b; P.c2w3 = b3_c2w; P.c2b3 = b3_c2b; P.lw3 = b3_lw; P.lb3 = b3_lb;
  P.c1w4 = b4_c1w; P.c1b4 = b4_c1b; P.c2w4 = b4_c2w; P.c2b4 = b4_c2b; P.lw4 = b4_lw; P.lb4 = b4_lb;
  P.g2p = g2p; P.g3p = g3p;
  P.stB2sk = stB2sk; P.stB2c1 = stB2c1; P.stB2c2 = stB2c2;
  P.stB3sk = stB3sk; P.stB3c1 = stB3c1; P.stB3c2 = stB3c2;
  P.stB4sk = stB4sk; P.stB4c1 = stB4c1; P.stB4c2 = stB4c2;
  P.out = out; P.bar = bar;
  k_tail<<<NWG, 256, 0, stream>>>(P);
  (void)st1; (void)st2; (void)b1_c2b;
}

// Round 2
// 511.060 us; speedup vs baseline: 1.2992x; 1.1547x over previous
//
#include <hip/hip_runtime.h>

#define NN 200000
#define NE 3200000
#define NWG 80
#define TT 1024
static constexpr float EPSV = 1e-5f;

// ---------------- CSR build: 2-level bucket sort ----------------
__global__ void k_cnt_prep(const int* __restrict__ ei, int* __restrict__ bktCnt,
                           const float* __restrict__ x, const float* __restrict__ pos,
                           float4* __restrict__ feat, float* __restrict__ xstats){
  __shared__ int cnt[256];
  __shared__ float sv[256], sq[256];
  int t = threadIdx.x;
  cnt[t] = 0;
  int i = blockIdx.x*256 + t;
  float xf = 0.f;
  if (i < NN){
    xf = x[i];
    feat[i] = make_float4(xf, pos[3*i], pos[3*i+1], 0.f);
  }
  sv[t] = (i < NN) ? xf : 0.f;
  sq[t] = sv[t]*sv[t];
  __syncthreads();
  int tile = blockIdx.x*4096;
  #pragma unroll
  for (int k = 0; k < 16; ++k){
    int e = tile + k*256 + t;
    if (e < NE) atomicAdd(&cnt[ei[NE+e]>>10], 1);
  }
  for (int o = 128; o > 0; o >>= 1){
    __syncthreads();
    if (t < o){ sv[t]+=sv[t+o]; sq[t]+=sq[t+o]; }
  }
  __syncthreads();
  if (t == 0){ atomicAdd(&xstats[0], sv[0]); atomicAdd(&xstats[1], sq[0]); }
  if (cnt[t]) atomicAdd(&bktCnt[t], cnt[t]);
}

__global__ void k_bktscan(const int* __restrict__ bktCnt, int* __restrict__ bktBase,
                          int* __restrict__ bktCur, int* __restrict__ off){
  __shared__ int s[256];
  int t = threadIdx.x;
  int v = bktCnt[t];
  s[t] = v; __syncthreads();
  for (int o = 1; o < 256; o <<= 1){
    int xv = (t >= o) ? s[t-o] : 0;
    __syncthreads(); s[t] += xv; __syncthreads();
  }
  int excl = s[t] - v;
  bktBase[t] = excl;
  bktCur[t]  = excl;
  if (t == 0){ bktBase[256] = NE; off[NN] = NE; }
}

__global__ void k_part1(const int* __restrict__ ei, int* __restrict__ bktCur,
                        int* __restrict__ pairs){
  __shared__ int cnt[256]; __shared__ int base[256]; __shared__ int rank[256];
  int t = threadIdx.x;   // 1024 threads
  if (t < 256) cnt[t] = 0;
  __syncthreads();
  int tile = blockIdx.x*16384;
  #pragma unroll
  for (int k = 0; k < 16; ++k){
    int e = tile + k*1024 + t;
    if (e < NE) atomicAdd(&cnt[ei[NE+e]>>10], 1);
  }
  __syncthreads();
  if (t < 256){
    base[t] = cnt[t] ? atomicAdd(&bktCur[t], cnt[t]) : 0;
    rank[t] = 0;
  }
  __syncthreads();
  #pragma unroll
  for (int k = 0; k < 16; ++k){
    int e = tile + k*1024 + t;
    if (e < NE){
      int d = ei[NE+e], s = ei[e];
      int b = d >> 10;
      int r = atomicAdd(&rank[b], 1);
      pairs[base[b] + r] = (s<<10) | (d & 1023);
    }
  }
}

__global__ void k_part2(const int* __restrict__ pairs, const int* __restrict__ bktBase,
                        int* __restrict__ off, int* __restrict__ srcs){
  __shared__ int hist[1024]; __shared__ int cur[1024];
  int b = blockIdx.x, t = threadIdx.x;
  int p0 = bktBase[b], p1 = bktBase[b+1];
  int cntB = p1 - p0;
  int dstBase = b << 10;
  int width = min(1024, NN - dstBase);
  hist[t] = 0; __syncthreads();
  for (int i = t; i < cntB; i += 1024) atomicAdd(&hist[pairs[p0+i] & 1023], 1);
  __syncthreads();
  int h0 = hist[t];
  for (int o = 1; o < 1024; o <<= 1){
    int xv = (t >= o) ? hist[t-o] : 0;
    __syncthreads(); hist[t] += xv; __syncthreads();
  }
  int excl = hist[t] - h0;
  if (t < width) off[dstBase + t] = p0 + excl;
  cur[t] = excl; __syncthreads();
  for (int i = t; i < cntB; i += 1024){
    int v = pairs[p0+i];
    int r = atomicAdd(&cur[v & 1023], 1);
    srcs[p0 + r] = v >> 10;
  }
}

// ---------------- Block 1 (N=200000, C=16) ----------------
__global__ void k_agg1(const float4* __restrict__ feat, const int* __restrict__ srcs,
                       const int* __restrict__ off, const float* __restrict__ pos,
                       const float* __restrict__ w48, const float* __restrict__ bias,
                       float4* __restrict__ H4){
  int t = threadIdx.x;
  int eidx = t & 15;
  int d = blockIdx.x*16 + (t >> 4);
  int s0 = off[d], s1 = off[d+1];
  float NI = -__builtin_inff();
  float m[16];
  #pragma unroll
  for (int c = 0; c < 16; ++c) m[c] = NI;
  for (int j = s0 + eidx; j < s1; j += 16){
    float4 f = feat[srcs[j]];
    #pragma unroll
    for (int c = 0; c < 16; ++c)
      m[c] = fmaxf(m[c], f.x*w48[c] + f.y*w48[16+c] + f.z*w48[32+c]);
  }
  #pragma unroll
  for (int mask = 1; mask < 16; mask <<= 1){
    #pragma unroll
    for (int c = 0; c < 16; ++c) m[c] = fmaxf(m[c], __shfl_xor(m[c], mask, 64));
  }
  if (eidx == 0){
    float o[16];
    if (s1 > s0){
      float px = pos[3*d], py = pos[3*d+1];
      #pragma unroll
      for (int c = 0; c < 16; ++c) o[c] = m[c] + bias[c] - (px*w48[16+c] + py*w48[32+c]);
    } else {
      #pragma unroll
      for (int c = 0; c < 16; ++c) o[c] = 0.f;
    }
    H4[d*4+0] = make_float4(o[0],o[1],o[2],o[3]);
    H4[d*4+1] = make_float4(o[4],o[5],o[6],o[7]);
    H4[d*4+2] = make_float4(o[8],o[9],o[10],o[11]);
    H4[d*4+3] = make_float4(o[12],o[13],o[14],o[15]);
  }
}

__global__ void k_agg16w(const float4* __restrict__ A4, const int* __restrict__ srcs,
                         const int* __restrict__ off, const float* __restrict__ pos,
                         const float* __restrict__ wpos, const float* __restrict__ bias,
                         float4* __restrict__ H4){
  int t = threadIdx.x;
  int lane = t & 63;
  int d = blockIdx.x*4 + (t >> 6);
  int eidx = lane >> 2;
  int cg = lane & 3;
  int s0 = off[d], s1 = off[d+1];
  float NI = -__builtin_inff();
  float4 m = make_float4(NI, NI, NI, NI);
  for (int j = s0 + eidx; j < s1; j += 16){
    int s = srcs[j];
    float4 a = A4[s*4 + cg];
    m.x = fmaxf(m.x, a.x); m.y = fmaxf(m.y, a.y);
    m.z = fmaxf(m.z, a.z); m.w = fmaxf(m.w, a.w);
  }
  #pragma unroll
  for (int mask = 4; mask <= 32; mask <<= 1){
    m.x = fmaxf(m.x, __shfl_xor(m.x, mask, 64));
    m.y = fmaxf(m.y, __shfl_xor(m.y, mask, 64));
    m.z = fmaxf(m.z, __shfl_xor(m.z, mask, 64));
    m.w = fmaxf(m.w, __shfl_xor(m.w, mask, 64));
  }
  if (eidx == 0){
    float4 val = make_float4(0.f, 0.f, 0.f, 0.f);
    if (s1 > s0){
      float px = pos[3*d], py = pos[3*d+1];
      int c0 = cg*4;
      val.x = m.x + bias[c0+0] - (px*wpos[c0+0] + py*wpos[16+c0+0]);
      val.y = m.y + bias[c0+1] - (px*wpos[c0+1] + py*wpos[16+c0+1]);
      val.z = m.z + bias[c0+2] - (px*wpos[c0+2] + py*wpos[16+c0+2]);
      val.w = m.w + bias[c0+3] - (px*wpos[c0+3] + py*wpos[16+c0+3]);
    }
    H4[d*4 + cg] = val;
  }
}

__global__ void k_stats16(const float* __restrict__ H, float* __restrict__ st){
  int t = threadIdx.x;
  float s = 0.f, q = 0.f;
  for (int idx = blockIdx.x*256 + t; idx < NN*16; idx += gridDim.x*256){
    float v = H[idx]; s += v; q += v*v;
  }
  __shared__ float sv[256], sq[256];
  sv[t] = s; sq[t] = q; __syncthreads();
  for (int o = 128; o >= 16; o >>= 1){
    if (t < o){ sv[t]+=sv[t+o]; sq[t]+=sq[t+o]; } __syncthreads();
  }
  if (t < 16){ atomicAdd(&st[t], sv[t]); atomicAdd(&st[16+t], sq[t]); }
}

__global__ void k_prep2(const float* __restrict__ Hraw, const float* __restrict__ st1,
                        const float* __restrict__ pos, const float* __restrict__ w,
                        float4* __restrict__ A4){
  int idx = blockIdx.x*blockDim.x + threadIdx.x;
  if (idx >= NN*4) return;
  int i = idx >> 2, cg = idx & 3;
  const float inv_n = 1.f/(float)NN;
  float acc0 = 0.f, acc1 = 0.f, acc2 = 0.f, acc3 = 0.f;
  #pragma unroll
  for (int k = 0; k < 16; ++k){
    float mk = st1[k]*inv_n;
    float vk = st1[16+k]*inv_n - mk*mk;
    float ik = rsqrtf(vk + EPSV);
    float h = fmaxf((Hraw[i*16+k]-mk)*ik, 0.f);
    acc0 += h*w[k*16 + cg*4 + 0];
    acc1 += h*w[k*16 + cg*4 + 1];
    acc2 += h*w[k*16 + cg*4 + 2];
    acc3 += h*w[k*16 + cg*4 + 3];
  }
  float px = pos[3*i], py = pos[3*i+1];
  int c0 = cg*4;
  acc0 += px*w[256+c0+0] + py*w[272+c0+0];
  acc1 += px*w[256+c0+1] + py*w[272+c0+1];
  acc2 += px*w[256+c0+2] + py*w[272+c0+2];
  acc3 += px*w[256+c0+3] + py*w[272+c0+3];
  A4[idx] = make_float4(acc0, acc1, acc2, acc3);
}

__global__ void k_comb_pool(const float* __restrict__ H, const float* __restrict__ x,
                            const float* __restrict__ pos, const float* __restrict__ lw,
                            const float* __restrict__ st2, const float* __restrict__ xstats,
                            float* __restrict__ mem){
  int idx = blockIdx.x*blockDim.x + threadIdx.x;
  if (idx >= NN*4) return;
  int i = idx >> 2, cg = idx & 3;
  const float inv_n = 1.f/(float)NN;
  float mx = xstats[0]*inv_n, vx = xstats[1]*inv_n - mx*mx;
  float xc = x[i] - mx;
  float px = pos[3*i], py = pos[3*i+1];
  int cx = (int)(px * 80.f / 240.f); cx = min(max(cx,0),79);
  int cy = (int)(py * 60.f / 180.f); cy = min(max(cy,0),59);
  float* mrow = &mem[(cy*80+cx)*16 + cg*4];
  #pragma unroll
  for (int k = 0; k < 4; ++k){
    int c = cg*4 + k;
    float m2 = st2[c]*inv_n, v2 = st2[16+c]*inv_n - m2*m2;
    float i2 = rsqrtf(v2 + EPSV);
    float a = lw[c];
    float sc = a * rsqrtf(a*a*vx + EPSV);
    float v = (H[i*16+c]-m2)*i2 + xc*sc;
    v = fmaxf(v, 0.f);
    atomicAdd(&mrow[k], v);
  }
}

// ---------------- Fused tail: halo-tiled, LDS-resident, flag-array barrier ----------------
__device__ __forceinline__ void stwt(float* p, float v){
  __hip_atomic_store(p, v, __ATOMIC_RELAXED, __HIP_MEMORY_SCOPE_AGENT);
}
__device__ __forceinline__ float ldwt(const float* p){
  return __hip_atomic_load(p, __ATOMIC_RELAXED, __HIP_MEMORY_SCOPE_AGENT);
}

// Flag-array barrier, monotonic generation (no reset round trip).
// bar layout (ints, zeroed at launch): flag[wg] at bar[32*wg] (own cacheline); gen at bar[2560].
__device__ __forceinline__ void gridbar(int* bar, int target){
  __syncthreads();   // compiler drains each wave's vm/lgkm before s_barrier
  const int t = threadIdx.x;
  if (blockIdx.x == 0){
    if (t >= 1 && t < NWG){
      while (__hip_atomic_load(bar + 32*t, __ATOMIC_RELAXED, __HIP_MEMORY_SCOPE_AGENT) < target)
        __builtin_amdgcn_s_sleep(1);
    }
    __syncthreads();
    if (t == 0)
      __hip_atomic_store(bar + 2560, target, __ATOMIC_RELAXED, __HIP_MEMORY_SCOPE_AGENT);
  } else {
    if (t == 0){
      __atomic_signal_fence(__ATOMIC_SEQ_CST);
      __builtin_amdgcn_s_waitcnt(0);   // this wave's stores durable before arrival flag
      __atomic_signal_fence(__ATOMIC_SEQ_CST);
      __hip_atomic_store(bar + 32*blockIdx.x, target, __ATOMIC_RELAXED, __HIP_MEMORY_SCOPE_AGENT);
      while (__hip_atomic_load(bar + 2560, __ATOMIC_RELAXED, __HIP_MEMORY_SCOPE_AGENT) < target)
        __builtin_amdgcn_s_sleep(2);
    }
    __syncthreads();
  }
}

struct TailP {
  const float *mem1;
  const float *p1w,*p1b,*p2w,*p2b,*p3w,*p3b;
  const float *c1w2,*c1b2,*c2w2,*c2b2,*lw2,*lb2;
  const float *c1w3,*c1b3,*c2w3,*c2b3,*lw3,*lb3;
  const float *c1w4,*c1b4,*c2w4,*c2b4,*lw4,*lb4;
  float *g2p,*g3p;
  float *stB2sk,*stB2c1,*stB2c2,*stB3sk,*stB3c1,*stB3c2,*stB4sk,*stB4c1,*stB4c2;
  float *out;
  int *bar;
};

// Phase A: G on T+2 halo (poollin for block2, ldwt(Gp) else); S = G@c1w on T+2;
//          SK = G@lw+lb on T (+stats); H1 = gridagg(S) on T+1 (+stats over owned T).
template<int GW,int GH,int TW,int TH,int K,int C,bool FIRST>
__device__ __forceinline__ void ph_A(float* buf, float* sv, float* sq,
    const float* __restrict__ Gglob, const float* __restrict__ plw, const float* __restrict__ plb,
    const float* __restrict__ c1w, const float* __restrict__ c1b,
    const float* __restrict__ lw, const float* __restrict__ lb,
    float* stH1, float* stSK, float sx, float sy, int tile)
{
  constexpr int W2=TW+4, nR2=W2*(TH+4);
  constexpr int W1=TW+2, nR1=W1*(TH+2);
  constexpr int nT=TW*TH, NTX=GW/TW;
  const int tx0=(tile%NTX)*TW, ty0=(tile/NTX)*TH;
  float* Gl=buf; float* Sl=Gl+nR2*K; float* H1l=Sl+nR2*C; float* SKl=H1l+nR1*C;
  const int t=threadIdx.x;
  if constexpr (FIRST){
    for (int e=t; e<nR2*K; e+=TT){
      int cell=e/K, k=e-cell*K;
      int gx=tx0-2+cell%W2, gy=ty0-2+cell/W2;
      Sl[e] = (gx>=0&&gx<GW&&gy>=0&&gy<GH) ? Gglob[(gy*GW+gx)*K+k] : 0.f;
    }
    __syncthreads();
    for (int e=t; e<nR2*K; e+=TT){
      int cell=e/K, c=e-cell*K;
      float acc=plb[c];
      #pragma unroll
      for (int k=0;k<K;++k) acc += Sl[cell*K+k]*plw[k*K+c];
      Gl[e] = (acc>1.f)?acc:0.f;
    }
  } else {
    for (int e=t; e<nR2*K; e+=TT){
      int cell=e/K, k=e-cell*K;
      int gx=tx0-2+cell%W2, gy=ty0-2+cell/W2;
      Gl[e] = (gx>=0&&gx<GW&&gy>=0&&gy<GH) ? ldwt(&Gglob[(gy*GW+gx)*K+k]) : 0.f;
    }
  }
  __syncthreads();
  // S on T+2 (out-of-grid cells compute from zeros; never read)
  for (int e=t; e<nR2*C; e+=TT){
    int cell=e/C, c=e-cell*C;
    float acc=0.f;
    #pragma unroll 8
    for (int k=0;k<K;++k) acc += Gl[cell*K+k]*c1w[k*C+c];
    Sl[e]=acc;
  }
  // SK on owned T + stats
  float ls=0.f,lq=0.f;
  for (int e=t; e<nT*C; e+=TT){
    int cell=e/C, c=e-cell*C;
    int lx=cell%TW, ly=cell/TW;
    int g2=(ly+2)*W2+(lx+2);
    float acc=lb[c];
    #pragma unroll 8
    for (int k=0;k<K;++k) acc += Gl[g2*K+k]*lw[k*C+c];
    SKl[e]=acc; ls+=acc; lq+=acc*acc;
  }
  __syncthreads();
  sv[t]=ls; sq[t]=lq; __syncthreads();
  for (int o=TT/2;o>=C;o>>=1){ if(t<o){sv[t]+=sv[t+o];sq[t]+=sq[t+o];} __syncthreads(); }
  if (t<C){ atomicAdd(&stSK[t],sv[t]); atomicAdd(&stSK[C+t],sq[t]); }
  __syncthreads();
  // H1 = gridagg(S) on T+1; stats over owned T only
  ls=0.f; lq=0.f;
  const float NI=-__builtin_inff();
  for (int e=t; e<nR1*C; e+=TT){
    int cell=e/C, c=e-cell*C;
    int lx=cell%W1, ly=cell/W1;
    int gx=tx0-1+lx, gy=ty0-1+ly;
    if (gx<0||gx>=GW||gy<0||gy>=GH) continue;
    float wx=c1w[K*C+c], wy=c1w[(K+1)*C+c];
    float m=NI;
    #pragma unroll
    for (int oy=-1;oy<=1;++oy){
      int ny=gy+oy; if (ny<0||ny>=GH) continue;
      #pragma unroll
      for (int ox=-1;ox<=1;++ox){
        int nx=gx+ox; if (nx<0||nx>=GW) continue;
        int l2=(ly+1+oy)*W2+(lx+1+ox);
        m=fmaxf(m, Sl[l2*C+c]+(ox*sx)*wx+(oy*sy)*wy);
      }
    }
    float val=m+c1b[c];
    H1l[e]=val;
    if (gx>=tx0&&gx<tx0+TW&&gy>=ty0&&gy<ty0+TH){ ls+=val; lq+=val*val; }
  }
  __syncthreads();
  sv[t]=ls; sq[t]=lq; __syncthreads();
  for (int o=TT/2;o>=C;o>>=1){ if(t<o){sv[t]+=sv[t+o];sq[t]+=sq[t+o];} __syncthreads(); }
  if (t<C){ atomicAdd(&stH1[t],sv[t]); atomicAdd(&stH1[C+t],sq[t]); }
}

// Phase B: normalize H1 (global stats) on T+1; S2 = relu(BN(H1))@c2w on T+1;
//          H2 = gridagg(S2) on T (+stats).
template<int GW,int GH,int TW,int TH,int K,int C>
__device__ __forceinline__ void ph_B(float* buf, float* sv, float* sq, float* la, float* lbv,
    const float* __restrict__ c2w, const float* __restrict__ c2b,
    const float* stH1, float* stH2, float sx, float sy, int tile)
{
  constexpr int W2=TW+4, nR2=W2*(TH+4);
  constexpr int W1=TW+2, nR1=W1*(TH+2);
  constexpr int nT=TW*TH, NTX=GW/TW;
  const int tx0=(tile%NTX)*TW, ty0=(tile/NTX)*TH;
  float* Gl=buf; float* Sl=Gl+nR2*K; float* H1l=Sl+nR2*C; float* SKl=H1l+nR1*C; float* H2l=SKl+nT*C;
  const int t=threadIdx.x;
  const float invn=1.f/(float)(GW*GH);
  if (t<C){
    float mk=ldwt(&stH1[t])*invn;
    float vk=ldwt(&stH1[C+t])*invn - mk*mk;
    float ik=rsqrtf(vk+EPSV);
    la[t]=ik; lbv[t]=-mk*ik;
  }
  __syncthreads();
  for (int e=t;e<nR1*C;e+=TT){
    int cell=e/C,c=e-cell*C;
    int gx=tx0-1+cell%W1, gy=ty0-1+cell/W1;
    if (gx<0||gx>=GW||gy<0||gy>=GH) continue;
    H1l[e]=fmaxf(H1l[e]*la[c]+lbv[c],0.f);
  }
  __syncthreads();
  // S2 on T+1 (region1 layout, reusing S buffer)
  for (int e=t;e<nR1*C;e+=TT){
    int cell=e/C,c=e-cell*C;
    int gx=tx0-1+cell%W1, gy=ty0-1+cell/W1;
    if (gx<0||gx>=GW||gy<0||gy>=GH) continue;
    float acc=0.f;
    #pragma unroll 8
    for (int k=0;k<C;++k) acc += H1l[cell*C+k]*c2w[k*C+c];
    Sl[e]=acc;
  }
  __syncthreads();
  float ls=0.f,lq=0.f;
  const float NI=-__builtin_inff();
  for (int e=t;e<nT*C;e+=TT){
    int cell=e/C,c=e-cell*C;
    int lx=cell%TW, ly=cell/TW;
    int gx=tx0+lx, gy=ty0+ly;
    float wx=c2w[C*C+c], wy=c2w[(C+1)*C+c];
    float m=NI;
    #pragma unroll
    for (int oy=-1;oy<=1;++oy){
      int ny=gy+oy; if (ny<0||ny>=GH) continue;
      #pragma unroll
      for (int ox=-1;ox<=1;++ox){
        int nx=gx+ox; if (nx<0||nx>=GW) continue;
        int l1=(ly+1+oy)*W1+(lx+1+ox);
        m=fmaxf(m, Sl[l1*C+c]+(ox*sx)*wx+(oy*sy)*wy);
      }
    }
    float val=m+c2b[c];
    H2l[e]=val; ls+=val; lq+=val*val;
  }
  __syncthreads();
  sv[t]=ls; sq[t]=lq; __syncthreads();
  for (int o=TT/2;o>=C;o>>=1){ if(t<o){sv[t]+=sv[t+o];sq[t]+=sq[t+o];} __syncthreads(); }
  if (t<C){ atomicAdd(&stH2[t],sv[t]); atomicAdd(&stH2[C+t],sq[t]); }
}

// Phase C: out = relu(BN(H2)+BN(SK)) on T -> global; 2x2 pool + poollin -> Gp.
template<int GW,int GH,int TW,int TH,int K,int C,bool POOL>
__device__ __forceinline__ void ph_C(float* buf, float* asv, float* asq, float* la, float* lbv,
    const float* stH2, const float* stSK,
    const float* __restrict__ pw, const float* __restrict__ pb,
    float* __restrict__ outg, float* __restrict__ Gpg, int tile)
{
  constexpr int W2=TW+4, nR2=W2*(TH+4);
  constexpr int W1=TW+2, nR1=W1*(TH+2);
  constexpr int nT=TW*TH, NTX=GW/TW;
  const int tx0=(tile%NTX)*TW, ty0=(tile/NTX)*TH;
  float* Gl=buf; float* Sl=Gl+nR2*K; float* H1l=Sl+nR2*C; float* SKl=H1l+nR1*C; float* H2l=SKl+nT*C;
  const int t=threadIdx.x;
  const float invn=1.f/(float)(GW*GH);
  if (t<C){
    float m2=ldwt(&stH2[t])*invn, v2=ldwt(&stH2[C+t])*invn-m2*m2;
    float i2=rsqrtf(v2+EPSV);
    la[t]=i2; lbv[t]=-m2*i2;
    float ms=ldwt(&stSK[t])*invn, vs=ldwt(&stSK[C+t])*invn-ms*ms;
    float is_=rsqrtf(vs+EPSV);
    asv[t]=is_; asq[t]=-ms*is_;
  }
  __syncthreads();
  float* OUTl=Sl;   // S2 dead; reuse as combined-output tile
  for (int e=t;e<nT*C;e+=TT){
    int cell=e/C,c=e-cell*C;
    int lx=cell%TW, ly=cell/TW;
    int gx=tx0+lx, gy=ty0+ly;
    float v=(H2l[e]*la[c]+lbv[c])+(SKl[e]*asv[c]+asq[c]);
    v=fmaxf(v,0.f);
    outg[(gy*GW+gx)*C+c]=v;   // plain store: flushed at kernel end
    OUTl[e]=v;
  }
  if constexpr (POOL){
    __syncthreads();
    constexpr int PTW=TW/2, PTH=TH/2, nP=PTW*PTH, PGW=GW/2;
    float* Ml=H1l;  // H1 dead; reuse as pooled sums
    for (int e=t;e<nP*C;e+=TT){
      int pc=e/C,c=e-pc*C;
      int plx=pc%PTW, ply=pc/PTW;
      float s=0.f;
      #pragma unroll
      for (int dy=0;dy<2;++dy)
        #pragma unroll
        for (int dx=0;dx<2;++dx)
          s += OUTl[((2*ply+dy)*TW+(2*plx+dx))*C+c];
      Ml[e]=s;
    }
    __syncthreads();
    for (int e=t;e<nP*C;e+=TT){
      int pc=e/C,c=e-pc*C;
      int plx=pc%PTW, ply=pc/PTW;
      float acc=pb[c];
      #pragma unroll 8
      for (int k=0;k<C;++k) acc += Ml[pc*C+k]*pw[k*C+c];
      int gpx=tx0/2+plx, gpy=ty0/2+ply;
      stwt(&Gpg[(gpy*PGW+gpx)*C+c], (acc>1.f)?acc:0.f);
    }
  }
  (void)nR1;
}

__global__ void __launch_bounds__(TT) k_tail(TailP P){
  __shared__ float sv[TT], sq[TT], la[128], lbv[128];
  __shared__ float buf[13824];   // 55.3 KB union of per-block halo tiles
  int* bar = P.bar;
  const int tile = blockIdx.x;

  // ---- block 2 (80x60, 16->32), tile 10x6, 80 tiles ----
  if (tile < 80) ph_A<80,60,10,6,16,32,true >(buf,sv,sq,P.mem1,P.p1w,P.p1b,P.c1w2,P.c1b2,P.lw2,P.lb2,P.stB2c1,P.stB2sk,3.f,3.f,tile);
  gridbar(bar, 1);
  if (tile < 80) ph_B<80,60,10,6,16,32>(buf,sv,sq,la,lbv,P.c2w2,P.c2b2,P.stB2c1,P.stB2c2,3.f,3.f,tile);
  gridbar(bar, 2);
  if (tile < 80) ph_C<80,60,10,6,16,32,true >(buf,sv,sq,la,lbv,P.stB2c2,P.stB2sk,P.p2w,P.p2b,P.out,P.g2p,tile);
  gridbar(bar, 3);
  // ---- block 3 (40x30, 32->64), tile 4x6, 50 tiles ----
  if (tile < 50) ph_A<40,30,4,6,32,64,false>(buf,sv,sq,P.g2p,nullptr,nullptr,P.c1w3,P.c1b3,P.lw3,P.lb3,P.stB3c1,P.stB3sk,6.f,6.f,tile);
  gridbar(bar, 4);
  if (tile < 50) ph_B<40,30,4,6,32,64>(buf,sv,sq,la,lbv,P.c2w3,P.c2b3,P.stB3c1,P.stB3c2,6.f,6.f,tile);
  gridbar(bar, 5);
  if (tile < 50) ph_C<40,30,4,6,32,64,true >(buf,sv,sq,la,lbv,P.stB3c2,P.stB3sk,P.p3w,P.p3b,P.out+153600,P.g3p,tile);
  gridbar(bar, 6);
  // ---- block 4 (20x15, 64->128), tile 2x3, 50 tiles, no pool ----
  if (tile < 50) ph_A<20,15,2,3,64,128,false>(buf,sv,sq,P.g3p,nullptr,nullptr,P.c1w4,P.c1b4,P.lw4,P.lb4,P.stB4c1,P.stB4sk,12.f,12.f,tile);
  gridbar(bar, 7);
  if (tile < 50) ph_B<20,15,2,3,64,128>(buf,sv,sq,la,lbv,P.c2w4,P.c2b4,P.stB4c1,P.stB4c2,12.f,12.f,tile);
  gridbar(bar, 8);
  if (tile < 50) ph_C<20,15,2,3,64,128,false>(buf,sv,sq,la,lbv,P.stB4c2,P.stB4sk,nullptr,nullptr,P.out+230400,nullptr,tile);
}

extern "C" void kernel_launch(void* const* d_in, const int* in_sizes, int n_in,
                              void* d_out, int out_size, void* d_ws, size_t ws_size,
                              hipStream_t stream){
  const float* x   = (const float*)d_in[0];
  const float* pos = (const float*)d_in[1];
  const int*   ei  = (const int*)d_in[2];
  const float* b1_c1w = (const float*)d_in[3];
  const float* b1_c1b = (const float*)d_in[4];
  const float* b1_c2w = (const float*)d_in[5];
  const float* b1_c2b = (const float*)d_in[6];
  const float* b1_lw  = (const float*)d_in[7];
  const float* b2_c1w = (const float*)d_in[9];
  const float* b2_c1b = (const float*)d_in[10];
  const float* b2_c2w = (const float*)d_in[11];
  const float* b2_c2b = (const float*)d_in[12];
  const float* b2_lw  = (const float*)d_in[13];
  const float* b2_lb  = (const float*)d_in[14];
  const float* b3_c1w = (const float*)d_in[15];
  const float* b3_c1b = (const float*)d_in[16];
  const float* b3_c2w = (const float*)d_in[17];
  const float* b3_c2b = (const float*)d_in[18];
  const float* b3_lw  = (const float*)d_in[19];
  const float* b3_lb  = (const float*)d_in[20];
  const float* b4_c1w = (const float*)d_in[21];
  const float* b4_c1b = (const float*)d_in[22];
  const float* b4_c2w = (const float*)d_in[23];
  const float* b4_c2b = (const float*)d_in[24];
  const float* b4_lw  = (const float*)d_in[25];
  const float* b4_lb  = (const float*)d_in[26];
  const float* p1w = (const float*)d_in[27];
  const float* p1b = (const float*)d_in[28];
  const float* p2w = (const float*)d_in[29];
  const float* p2b = (const float*)d_in[30];
  const float* p3w = (const float*)d_in[31];
  const float* p3b = (const float*)d_in[32];
  float* out = (float*)d_out;

  // ---- workspace carve ----
  float4* feat = (float4*)d_ws;       // NN float4 (3.2MB)
  float* A  = (float*)(feat + NN);    // NN*16 fp32; pairs + inter-block buffers ALIAS (A dead then)
  int* pairs = (int*)A;               // NE ints — ALIAS
  float* g2p  = A;                    // 1200*32 — alias, A dead after k_agg16w/k_comb_pool
  float* g3p  = A + 38400;            // 300*64
  float* H  = A + NN*16;              // NN*16
  // Z region (single memset): bucket counters, barrier flags, stats, mem1
  int* bktCnt  = (int*)(H + NN*16);   // 256
  int* bktBase = bktCnt + 256;        // 257
  int* bktCur  = bktBase + 257;       // ends 769, pad to 1024
  int* bar     = bktCnt + 1024;       // flags: 80 x stride-32 + gen at [2560]; pad to 2624
  float* STz   = (float*)(bktCnt + 1024 + 2624);
  float* xstats = STz;                // 2
  float* st1    = STz + 16;
  float* st2    = STz + 64;
  float* stB2sk = STz + 128;
  float* stB2c1 = STz + 192;
  float* stB2c2 = STz + 256;
  float* stB3sk = STz + 320;
  float* stB3c1 = STz + 448;
  float* stB3c2 = STz + 576;
  float* stB4sk = STz + 704;
  float* stB4c1 = STz + 960;
  float* stB4c2 = STz + 1216;         // ..1471, pad to 1536
  float* mem1   = STz + 1536;         // 76800
  const size_t ZBYTES = (size_t)(1024 + 2624 + 1536 + 76800) * 4;
  int* off    = (int*)(mem1 + 76800); // NN+1
  int* srcs   = off + (NN+1);         // NE

  hipMemsetAsync(bktCnt, 0, ZBYTES, stream);

  const int B = 256;
  // CSR build (fused with feat/xstats prep)
  k_cnt_prep<<<(NE+4095)/4096, 256, 0, stream>>>(ei, bktCnt, x, pos, feat, xstats);
  k_bktscan <<<1, 256, 0, stream>>>(bktCnt, bktBase, bktCur, off);
  k_part1   <<<(NE+16383)/16384, 1024, 0, stream>>>(ei, bktCur, pairs);
  k_part2   <<<196, 1024, 0, stream>>>(pairs, bktBase, off, srcs);

  // Block 1
  k_agg1    <<<NN/16, B, 0, stream>>>(feat, srcs, off, pos, b1_c1w, b1_c1b, (float4*)H);
  k_stats16 <<<256, B, 0, stream>>>(H, st1);
  k_prep2   <<<(NN*4+B-1)/B, B, 0, stream>>>(H, st1, pos, b1_c2w, (float4*)A);
  k_agg16w  <<<NN/4, B, 0, stream>>>((const float4*)A, srcs, off, pos, b1_c2w+256, b1_c2b, (float4*)H);
  k_stats16 <<<256, B, 0, stream>>>(H, st2);
  k_comb_pool<<<(NN*4+B-1)/B, B, 0, stream>>>(H, x, pos, b1_lw, st2, xstats, mem1);

  // Fused tail: halo-tiled LDS-resident blocks 2-4, flag-array barrier, 1024 threads/WG
  TailP P;
  P.mem1 = mem1;
  P.p1w = p1w; P.p1b = p1b; P.p2w = p2w; P.p2b = p2b; P.p3w = p3w; P.p3b = p3b;
  P.c1w2 = b2_c1w; P.c1b2 = b2_c1b; P.c2w2 = b2_c2w; P.c2b2 = b2_c2b; P.lw2 = b2_lw; P.lb2 = b2_lb;
  P.c1w3 = b3_c1w; P.c1b3 = b3_c1b; P.c2w3 = b3_c2w; P.c2b3 = b3_c2b; P.lw3 = b3_lw; P.lb3 = b3_lb;
  P.c1w4 = b4_c1w; P.c1b4 = b4_c1b; P.c2w4 = b4_c2w; P.c2b4 = b4_c2b; P.lw4 = b4_lw; P.lb4 = b4_lb;
  P.g2p = g2p; P.g3p = g3p;
  P.stB2sk = stB2sk; P.stB2c1 = stB2c1; P.stB2c2 = stB2c2;
  P.stB3sk = stB3sk; P.stB3c1 = stB3c1; P.stB3c2 = stB3c2;
  P.stB4sk = stB4sk; P.stB4c1 = stB4c1; P.stB4c2 = stB4c2;
  P.out = out; P.bar = bar;
  k_tail<<<NWG, TT, 0, stream>>>(P);
  (void)st1; (void)st2; (void)b1_c2b;
}

// Round 4
// 483.624 us; speedup vs baseline: 1.3729x; 1.0567x over previous
//
#include <hip/hip_runtime.h>

#define NN 200000
#define NE 3200000
#define NWG 80
#define TT 1024
static constexpr float EPSV = 1e-5f;

// ---------------- CSR build: bucket sort (2 passes, no within-bucket scatter) ----------------
__global__ void k_cnt_prep(const int* __restrict__ ei, int* __restrict__ bktCnt,
                           const float* __restrict__ x, const float* __restrict__ pos,
                           float4* __restrict__ feat, float* __restrict__ xstats){
  __shared__ int cnt[256];
  __shared__ float sv[256], sq[256];
  int t = threadIdx.x;
  cnt[t] = 0;
  int i = blockIdx.x*256 + t;
  float xf = 0.f;
  if (i < NN){
    xf = x[i];
    feat[i] = make_float4(xf, pos[3*i], pos[3*i+1], 0.f);
  }
  sv[t] = (i < NN) ? xf : 0.f;
  sq[t] = sv[t]*sv[t];
  __syncthreads();
  int tile = blockIdx.x*4096;
  #pragma unroll
  for (int k = 0; k < 16; ++k){
    int e = tile + k*256 + t;
    if (e < NE) atomicAdd(&cnt[ei[NE+e]>>10], 1);
  }
  for (int o = 128; o > 0; o >>= 1){
    __syncthreads();
    if (t < o){ sv[t]+=sv[t+o]; sq[t]+=sq[t+o]; }
  }
  __syncthreads();
  if (t == 0){ atomicAdd(&xstats[0], sv[0]); atomicAdd(&xstats[1], sq[0]); }
  if (cnt[t]) atomicAdd(&bktCnt[t], cnt[t]);
}

__global__ void k_bktscan(const int* __restrict__ bktCnt, int* __restrict__ bktBase,
                          int* __restrict__ bktCur){
  __shared__ int s[256];
  int t = threadIdx.x;
  int v = bktCnt[t];
  s[t] = v; __syncthreads();
  for (int o = 1; o < 256; o <<= 1){
    int xv = (t >= o) ? s[t-o] : 0;
    __syncthreads(); s[t] += xv; __syncthreads();
  }
  int excl = s[t] - v;
  bktBase[t] = excl;
  bktCur[t]  = excl;
  if (t == 0){ bktBase[256] = NE; }
}

__global__ void k_part1(const int* __restrict__ ei, int* __restrict__ bktCur,
                        int* __restrict__ pairs){
  __shared__ int cnt[256]; __shared__ int base[256]; __shared__ int rank[256];
  int t = threadIdx.x;   // 1024 threads
  if (t < 256) cnt[t] = 0;
  __syncthreads();
  int tile = blockIdx.x*16384;
  #pragma unroll
  for (int k = 0; k < 16; ++k){
    int e = tile + k*1024 + t;
    if (e < NE) atomicAdd(&cnt[ei[NE+e]>>10], 1);
  }
  __syncthreads();
  if (t < 256){
    base[t] = cnt[t] ? atomicAdd(&bktCur[t], cnt[t]) : 0;
    rank[t] = 0;
  }
  __syncthreads();
  #pragma unroll
  for (int k = 0; k < 16; ++k){
    int e = tile + k*1024 + t;
    if (e < NE){
      int d = ei[NE+e], s = ei[e];
      int b = d >> 10;
      int r = atomicAdd(&rank[b], 1);
      pairs[base[b] + r] = (s<<10) | (d & 1023);
    }
  }
}

// ---------------- order-preserving float<->uint for atomicMax ----------------
__device__ __forceinline__ unsigned fenc(float f){
  unsigned u = __float_as_uint(f);
  return (u >> 31) ? ~u : (u | 0x80000000u);
}
__device__ __forceinline__ float fdec(unsigned k){
  unsigned u = (k >> 31) ? (k ^ 0x80000000u) : ~k;
  return __uint_as_float(u);
}
#define ENC_NI 0x007FFFFFu   /* fenc(-inf) */

// ---------------- Block 1 conv1: bucket-resident LDS max-scatter, fused stats ----------------
__global__ void __launch_bounds__(1024) k_aggA(const int* __restrict__ pairs, const int* __restrict__ bktBase,
    const float4* __restrict__ feat, const float* __restrict__ pos,
    const float* __restrict__ w48, const float* __restrict__ bias,
    float* __restrict__ H, float* __restrict__ st){
  __shared__ unsigned acc[16384];   // 1024 dst x 16 ch, 64KB
  const int b = blockIdx.x, t = threadIdx.x;
  for (int i = t; i < 16384; i += 1024) acc[i] = ENC_NI;
  float w0[16], w1[16], w2[16];
  #pragma unroll
  for (int c = 0; c < 16; ++c){ w0[c]=w48[c]; w1[c]=w48[16+c]; w2[c]=w48[32+c]; }
  const int p0 = bktBase[b], p1 = bktBase[b+1];
  __syncthreads();
  for (int j = p0 + t; j < p1; j += 1024){
    int pr = pairs[j];
    float4 f = feat[pr >> 10];
    int dbase = (pr & 1023) * 16;
    #pragma unroll
    for (int c = 0; c < 16; ++c){
      float m = f.x*w0[c] + f.y*w1[c] + f.z*w2[c];
      atomicMax(&acc[dbase + c], fenc(m));
    }
  }
  __syncthreads();
  const int base = b << 10;
  const int width = min(1024, NN - base);
  const int c = t & 15;
  const float b_c = bias[c], w1c = w48[16+c], w2c = w48[32+c];
  float ls = 0.f, lq = 0.f;
  for (int i = t; i < width*16; i += 1024){
    int dl = i >> 4, d = base + dl;
    float o = 0.f;
    if (acc[dl*16] != ENC_NI){
      float px = pos[3*d], py = pos[3*d+1];
      o = fdec(acc[i]) + b_c - (px*w1c + py*w2c);
    }
    H[base*16 + i] = o;
    ls += o; lq += o*o;
  }
  __syncthreads();
  float* sv = (float*)acc; float* sq = sv + 1024;
  sv[t] = ls; sq[t] = lq; __syncthreads();
  for (int o2 = 512; o2 >= 16; o2 >>= 1){ if (t < o2){ sv[t]+=sv[t+o2]; sq[t]+=sq[t+o2]; } __syncthreads(); }
  if (t < 16){ atomicAdd(&st[t], sv[t]); atomicAdd(&st[16+t], sq[t]); }
}

// ---------------- Block 1 conv2: same structure over precomputed A ----------------
__global__ void __launch_bounds__(1024) k_aggB(const int* __restrict__ pairs, const int* __restrict__ bktBase,
    const float4* __restrict__ A4, const float* __restrict__ pos,
    const float* __restrict__ wpos, const float* __restrict__ bias,
    float* __restrict__ H, float* __restrict__ st){
  __shared__ unsigned acc[16384];
  const int b = blockIdx.x, t = threadIdx.x;
  for (int i = t; i < 16384; i += 1024) acc[i] = ENC_NI;
  const int p0 = bktBase[b], p1 = bktBase[b+1];
  __syncthreads();
  for (int j = p0 + t; j < p1; j += 1024){
    int pr = pairs[j];
    int s = pr >> 10;
    int dbase = (pr & 1023) * 16;
    float4 a0 = A4[s*4+0], a1 = A4[s*4+1], a2 = A4[s*4+2], a3 = A4[s*4+3];
    atomicMax(&acc[dbase+ 0], fenc(a0.x));
    atomicMax(&acc[dbase+ 1], fenc(a0.y));
    atomicMax(&acc[dbase+ 2], fenc(a0.z));
    atomicMax(&acc[dbase+ 3], fenc(a0.w));
    atomicMax(&acc[dbase+ 4], fenc(a1.x));
    atomicMax(&acc[dbase+ 5], fenc(a1.y));
    atomicMax(&acc[dbase+ 6], fenc(a1.z));
    atomicMax(&acc[dbase+ 7], fenc(a1.w));
    atomicMax(&acc[dbase+ 8], fenc(a2.x));
    atomicMax(&acc[dbase+ 9], fenc(a2.y));
    atomicMax(&acc[dbase+10], fenc(a2.z));
    atomicMax(&acc[dbase+11], fenc(a2.w));
    atomicMax(&acc[dbase+12], fenc(a3.x));
    atomicMax(&acc[dbase+13], fenc(a3.y));
    atomicMax(&acc[dbase+14], fenc(a3.z));
    atomicMax(&acc[dbase+15], fenc(a3.w));
  }
  __syncthreads();
  const int base = b << 10;
  const int width = min(1024, NN - base);
  const int c = t & 15;
  const float b_c = bias[c], w1c = wpos[c], w2c = wpos[16+c];
  float ls = 0.f, lq = 0.f;
  for (int i = t; i < width*16; i += 1024){
    int dl = i >> 4, d = base + dl;
    float o = 0.f;
    if (acc[dl*16] != ENC_NI){
      float px = pos[3*d], py = pos[3*d+1];
      o = fdec(acc[i]) + b_c - (px*w1c + py*w2c);
    }
    H[base*16 + i] = o;
    ls += o; lq += o*o;
  }
  __syncthreads();
  float* sv = (float*)acc; float* sq = sv + 1024;
  sv[t] = ls; sq[t] = lq; __syncthreads();
  for (int o2 = 512; o2 >= 16; o2 >>= 1){ if (t < o2){ sv[t]+=sv[t+o2]; sq[t]+=sq[t+o2]; } __syncthreads(); }
  if (t < 16){ atomicAdd(&st[t], sv[t]); atomicAdd(&st[16+t], sq[t]); }
}

__global__ void k_prep2(const float* __restrict__ Hraw, const float* __restrict__ st1,
                        const float* __restrict__ pos, const float* __restrict__ w,
                        float4* __restrict__ A4){
  int idx = blockIdx.x*blockDim.x + threadIdx.x;
  if (idx >= NN*4) return;
  int i = idx >> 2, cg = idx & 3;
  const float inv_n = 1.f/(float)NN;
  float acc0 = 0.f, acc1 = 0.f, acc2 = 0.f, acc3 = 0.f;
  #pragma unroll
  for (int k = 0; k < 16; ++k){
    float mk = st1[k]*inv_n;
    float vk = st1[16+k]*inv_n - mk*mk;
    float ik = rsqrtf(vk + EPSV);
    float h = fmaxf((Hraw[i*16+k]-mk)*ik, 0.f);
    acc0 += h*w[k*16 + cg*4 + 0];
    acc1 += h*w[k*16 + cg*4 + 1];
    acc2 += h*w[k*16 + cg*4 + 2];
    acc3 += h*w[k*16 + cg*4 + 3];
  }
  float px = pos[3*i], py = pos[3*i+1];
  int c0 = cg*4;
  acc0 += px*w[256+c0+0] + py*w[272+c0+0];
  acc1 += px*w[256+c0+1] + py*w[272+c0+1];
  acc2 += px*w[256+c0+2] + py*w[272+c0+2];
  acc3 += px*w[256+c0+3] + py*w[272+c0+3];
  A4[idx] = make_float4(acc0, acc1, acc2, acc3);
}

__global__ void k_comb_pool(const float* __restrict__ H, const float* __restrict__ x,
                            const float* __restrict__ pos, const float* __restrict__ lw,
                            const float* __restrict__ st2, const float* __restrict__ xstats,
                            float* __restrict__ mem){
  int idx = blockIdx.x*blockDim.x + threadIdx.x;
  if (idx >= NN*4) return;
  int i = idx >> 2, cg = idx & 3;
  const float inv_n = 1.f/(float)NN;
  float mx = xstats[0]*inv_n, vx = xstats[1]*inv_n - mx*mx;
  float xc = x[i] - mx;
  float px = pos[3*i], py = pos[3*i+1];
  int cx = (int)(px * 80.f / 240.f); cx = min(max(cx,0),79);
  int cy = (int)(py * 60.f / 180.f); cy = min(max(cy,0),59);
  float* mrow = &mem[(cy*80+cx)*16 + cg*4];
  #pragma unroll
  for (int k = 0; k < 4; ++k){
    int c = cg*4 + k;
    float m2 = st2[c]*inv_n, v2 = st2[16+c]*inv_n - m2*m2;
    float i2 = rsqrtf(v2 + EPSV);
    float a = lw[c];
    float sc = a * rsqrtf(a*a*vx + EPSV);
    float v = (H[i*16+c]-m2)*i2 + xc*sc;
    v = fmaxf(v, 0.f);
    atomicAdd(&mrow[k], v);
  }
}

// ---------------- Fused tail: halo-tiled, LDS-resident, flag-array barrier ----------------
__device__ __forceinline__ void stwt(float* p, float v){
  __hip_atomic_store(p, v, __ATOMIC_RELAXED, __HIP_MEMORY_SCOPE_AGENT);
}
__device__ __forceinline__ float ldwt(const float* p){
  return __hip_atomic_load(p, __ATOMIC_RELAXED, __HIP_MEMORY_SCOPE_AGENT);
}

// Flag-array barrier, monotonic generation (no reset round trip).
// bar layout (ints, zeroed at launch): flag[wg] at bar[32*wg] (own cacheline); gen at bar[2560].
__device__ __forceinline__ void gridbar(int* bar, int target){
  __syncthreads();   // compiler drains each wave's vm/lgkm before s_barrier
  const int t = threadIdx.x;
  if (blockIdx.x == 0){
    if (t >= 1 && t < NWG){
      while (__hip_atomic_load(bar + 32*t, __ATOMIC_RELAXED, __HIP_MEMORY_SCOPE_AGENT) < target)
        __builtin_amdgcn_s_sleep(1);
    }
    __syncthreads();
    if (t == 0)
      __hip_atomic_store(bar + 2560, target, __ATOMIC_RELAXED, __HIP_MEMORY_SCOPE_AGENT);
  } else {
    if (t == 0){
      __atomic_signal_fence(__ATOMIC_SEQ_CST);
      __builtin_amdgcn_s_waitcnt(0);   // this wave's stores durable before arrival flag
      __atomic_signal_fence(__ATOMIC_SEQ_CST);
      __hip_atomic_store(bar + 32*blockIdx.x, target, __ATOMIC_RELAXED, __HIP_MEMORY_SCOPE_AGENT);
      while (__hip_atomic_load(bar + 2560, __ATOMIC_RELAXED, __HIP_MEMORY_SCOPE_AGENT) < target)
        __builtin_amdgcn_s_sleep(2);
    }
    __syncthreads();
  }
}

struct TailP {
  const float *mem1;
  const float *p1w,*p1b,*p2w,*p2b,*p3w,*p3b;
  const float *c1w2,*c1b2,*c2w2,*c2b2,*lw2,*lb2;
  const float *c1w3,*c1b3,*c2w3,*c2b3,*lw3,*lb3;
  const float *c1w4,*c1b4,*c2w4,*c2b4,*lw4,*lb4;
  float *g2p,*g3p;
  float *stB2sk,*stB2c1,*stB2c2,*stB3sk,*stB3c1,*stB3c2,*stB4sk,*stB4c1,*stB4c2;
  float *out;
  int *bar;
};

// Phase A: G on T+2 halo (poollin for block2, ldwt(Gp) else); S = G@c1w on T+2;
//          SK = G@lw+lb on T (+stats); H1 = gridagg(S) on T+1 (+stats over owned T).
template<int GW,int GH,int TW,int TH,int K,int C,bool FIRST>
__device__ __forceinline__ void ph_A(float* buf, float* sv, float* sq,
    const float* __restrict__ Gglob, const float* __restrict__ plw, const float* __restrict__ plb,
    const float* __restrict__ c1w, const float* __restrict__ c1b,
    const float* __restrict__ lw, const float* __restrict__ lb,
    float* stH1, float* stSK, float sx, float sy, int tile)
{
  constexpr int W2=TW+4, nR2=W2*(TH+4);
  constexpr int W1=TW+2, nR1=W1*(TH+2);
  constexpr int nT=TW*TH, NTX=GW/TW;
  const int tx0=(tile%NTX)*TW, ty0=(tile/NTX)*TH;
  float* Gl=buf; float* Sl=Gl+nR2*K; float* H1l=Sl+nR2*C; float* SKl=H1l+nR1*C;
  const int t=threadIdx.x;
  if constexpr (FIRST){
    for (int e=t; e<nR2*K; e+=TT){
      int cell=e/K, k=e-cell*K;
      int gx=tx0-2+cell%W2, gy=ty0-2+cell/W2;
      Sl[e] = (gx>=0&&gx<GW&&gy>=0&&gy<GH) ? Gglob[(gy*GW+gx)*K+k] : 0.f;
    }
    __syncthreads();
    for (int e=t; e<nR2*K; e+=TT){
      int cell=e/K, c=e-cell*K;
      float acc=plb[c];
      #pragma unroll
      for (int k=0;k<K;++k) acc += Sl[cell*K+k]*plw[k*K+c];
      Gl[e] = (acc>1.f)?acc:0.f;
    }
  } else {
    for (int e=t; e<nR2*K; e+=TT){
      int cell=e/K, k=e-cell*K;
      int gx=tx0-2+cell%W2, gy=ty0-2+cell/W2;
      Gl[e] = (gx>=0&&gx<GW&&gy>=0&&gy<GH) ? ldwt(&Gglob[(gy*GW+gx)*K+k]) : 0.f;
    }
  }
  __syncthreads();
  // S on T+2 (out-of-grid cells compute from zeros; never read)
  for (int e=t; e<nR2*C; e+=TT){
    int cell=e/C, c=e-cell*C;
    float acc=0.f;
    #pragma unroll 8
    for (int k=0;k<K;++k) acc += Gl[cell*K+k]*c1w[k*C+c];
    Sl[e]=acc;
  }
  // SK on owned T + stats
  float ls=0.f,lq=0.f;
  for (int e=t; e<nT*C; e+=TT){
    int cell=e/C, c=e-cell*C;
    int lx=cell%TW, ly=cell/TW;
    int g2=(ly+2)*W2+(lx+2);
    float acc=lb[c];
    #pragma unroll 8
    for (int k=0;k<K;++k) acc += Gl[g2*K+k]*lw[k*C+c];
    SKl[e]=acc; ls+=acc; lq+=acc*acc;
  }
  __syncthreads();
  sv[t]=ls; sq[t]=lq; __syncthreads();
  for (int o=TT/2;o>=C;o>>=1){ if(t<o){sv[t]+=sv[t+o];sq[t]+=sq[t+o];} __syncthreads(); }
  if (t<C){ atomicAdd(&stSK[t],sv[t]); atomicAdd(&stSK[C+t],sq[t]); }
  __syncthreads();
  // H1 = gridagg(S) on T+1; stats over owned T only
  ls=0.f; lq=0.f;
  const float NI=-__builtin_inff();
  for (int e=t; e<nR1*C; e+=TT){
    int cell=e/C, c=e-cell*C;
    int lx=cell%W1, ly=cell/W1;
    int gx=tx0-1+lx, gy=ty0-1+ly;
    if (gx<0||gx>=GW||gy<0||gy>=GH) continue;
    float wx=c1w[K*C+c], wy=c1w[(K+1)*C+c];
    float m=NI;
    #pragma unroll
    for (int oy=-1;oy<=1;++oy){
      int ny=gy+oy; if (ny<0||ny>=GH) continue;
      #pragma unroll
      for (int ox=-1;ox<=1;++ox){
        int nx=gx+ox; if (nx<0||nx>=GW) continue;
        int l2=(ly+1+oy)*W2+(lx+1+ox);
        m=fmaxf(m, Sl[l2*C+c]+(ox*sx)*wx+(oy*sy)*wy);
      }
    }
    float val=m+c1b[c];
    H1l[e]=val;
    if (gx>=tx0&&gx<tx0+TW&&gy>=ty0&&gy<ty0+TH){ ls+=val; lq+=val*val; }
  }
  __syncthreads();
  sv[t]=ls; sq[t]=lq; __syncthreads();
  for (int o=TT/2;o>=C;o>>=1){ if(t<o){sv[t]+=sv[t+o];sq[t]+=sq[t+o];} __syncthreads(); }
  if (t<C){ atomicAdd(&stH1[t],sv[t]); atomicAdd(&stH1[C+t],sq[t]); }
}

// Phase B: normalize H1 (global stats) on T+1; S2 = relu(BN(H1))@c2w on T+1;
//          H2 = gridagg(S2) on T (+stats).
template<int GW,int GH,int TW,int TH,int K,int C>
__device__ __forceinline__ void ph_B(float* buf, float* sv, float* sq, float* la, float* lbv,
    const float* __restrict__ c2w, const float* __restrict__ c2b,
    const float* stH1, float* stH2, float sx, float sy, int tile)
{
  constexpr int W2=TW+4, nR2=W2*(TH+4);
  constexpr int W1=TW+2, nR1=W1*(TH+2);
  constexpr int nT=TW*TH, NTX=GW/TW;
  const int tx0=(tile%NTX)*TW, ty0=(tile/NTX)*TH;
  float* Gl=buf; float* Sl=Gl+nR2*K; float* H1l=Sl+nR2*C; float* SKl=H1l+nR1*C; float* H2l=SKl+nT*C;
  const int t=threadIdx.x;
  const float invn=1.f/(float)(GW*GH);
  if (t<C){
    float mk=ldwt(&stH1[t])*invn;
    float vk=ldwt(&stH1[C+t])*invn - mk*mk;
    float ik=rsqrtf(vk+EPSV);
    la[t]=ik; lbv[t]=-mk*ik;
  }
  __syncthreads();
  for (int e=t;e<nR1*C;e+=TT){
    int cell=e/C,c=e-cell*C;
    int gx=tx0-1+cell%W1, gy=ty0-1+cell/W1;
    if (gx<0||gx>=GW||gy<0||gy>=GH) continue;
    H1l[e]=fmaxf(H1l[e]*la[c]+lbv[c],0.f);
  }
  __syncthreads();
  // S2 on T+1 (region1 layout, reusing S buffer)
  for (int e=t;e<nR1*C;e+=TT){
    int cell=e/C,c=e-cell*C;
    int gx=tx0-1+cell%W1, gy=ty0-1+cell/W1;
    if (gx<0||gx>=GW||gy<0||gy>=GH) continue;
    float acc=0.f;
    #pragma unroll 8
    for (int k=0;k<C;++k) acc += H1l[cell*C+k]*c2w[k*C+c];
    Sl[e]=acc;
  }
  __syncthreads();
  float ls=0.f,lq=0.f;
  const float NI=-__builtin_inff();
  for (int e=t;e<nT*C;e+=TT){
    int cell=e/C,c=e-cell*C;
    int lx=cell%TW, ly=cell/TW;
    int gx=tx0+lx, gy=ty0+ly;
    float wx=c2w[C*C+c], wy=c2w[(C+1)*C+c];
    float m=NI;
    #pragma unroll
    for (int oy=-1;oy<=1;++oy){
      int ny=gy+oy; if (ny<0||ny>=GH) continue;
      #pragma unroll
      for (int ox=-1;ox<=1;++ox){
        int nx=gx+ox; if (nx<0||nx>=GW) continue;
        int l1=(ly+1+oy)*W1+(lx+1+ox);
        m=fmaxf(m, Sl[l1*C+c]+(ox*sx)*wx+(oy*sy)*wy);
      }
    }
    float val=m+c2b[c];
    H2l[e]=val; ls+=val; lq+=val*val;
  }
  __syncthreads();
  sv[t]=ls; sq[t]=lq; __syncthreads();
  for (int o=TT/2;o>=C;o>>=1){ if(t<o){sv[t]+=sv[t+o];sq[t]+=sq[t+o];} __syncthreads(); }
  if (t<C){ atomicAdd(&stH2[t],sv[t]); atomicAdd(&stH2[C+t],sq[t]); }
}

// Phase C: out = relu(BN(H2)+BN(SK)) on T -> global; 2x2 pool + poollin -> Gp.
template<int GW,int GH,int TW,int TH,int K,int C,bool POOL>
__device__ __forceinline__ void ph_C(float* buf, float* asv, float* asq, float* la, float* lbv,
    const float* stH2, const float* stSK,
    const float* __restrict__ pw, const float* __restrict__ pb,
    float* __restrict__ outg, float* __restrict__ Gpg, int tile)
{
  constexpr int W2=TW+4, nR2=W2*(TH+4);
  constexpr int W1=TW+2, nR1=W1*(TH+2);
  constexpr int nT=TW*TH, NTX=GW/TW;
  const int tx0=(tile%NTX)*TW, ty0=(tile/NTX)*TH;
  float* Gl=buf; float* Sl=Gl+nR2*K; float* H1l=Sl+nR2*C; float* SKl=H1l+nR1*C; float* H2l=SKl+nT*C;
  const int t=threadIdx.x;
  const float invn=1.f/(float)(GW*GH);
  if (t<C){
    float m2=ldwt(&stH2[t])*invn, v2=ldwt(&stH2[C+t])*invn-m2*m2;
    float i2=rsqrtf(v2+EPSV);
    la[t]=i2; lbv[t]=-m2*i2;
    float ms=ldwt(&stSK[t])*invn, vs=ldwt(&stSK[C+t])*invn-ms*ms;
    float is_=rsqrtf(vs+EPSV);
    asv[t]=is_; asq[t]=-ms*is_;
  }
  __syncthreads();
  float* OUTl=Sl;   // S2 dead; reuse as combined-output tile
  for (int e=t;e<nT*C;e+=TT){
    int cell=e/C,c=e-cell*C;
    int lx=cell%TW, ly=cell/TW;
    int gx=tx0+lx, gy=ty0+ly;
    float v=(H2l[e]*la[c]+lbv[c])+(SKl[e]*asv[c]+asq[c]);
    v=fmaxf(v,0.f);
    outg[(gy*GW+gx)*C+c]=v;   // plain store: flushed at kernel end
    OUTl[e]=v;
  }
  if constexpr (POOL){
    __syncthreads();
    constexpr int PTW=TW/2, PTH=TH/2, nP=PTW*PTH, PGW=GW/2;
    float* Ml=H1l;  // H1 dead; reuse as pooled sums
    for (int e=t;e<nP*C;e+=TT){
      int pc=e/C,c=e-pc*C;
      int plx=pc%PTW, ply=pc/PTW;
      float s=0.f;
      #pragma unroll
      for (int dy=0;dy<2;++dy)
        #pragma unroll
        for (int dx=0;dx<2;++dx)
          s += OUTl[((2*ply+dy)*TW+(2*plx+dx))*C+c];
      Ml[e]=s;
    }
    __syncthreads();
    for (int e=t;e<nP*C;e+=TT){
      int pc=e/C,c=e-pc*C;
      int plx=pc%PTW, ply=pc/PTW;
      float acc=pb[c];
      #pragma unroll 8
      for (int k=0;k<C;++k) acc += Ml[pc*C+k]*pw[k*C+c];
      int gpx=tx0/2+plx, gpy=ty0/2+ply;
      stwt(&Gpg[(gpy*PGW+gpx)*C+c], (acc>1.f)?acc:0.f);
    }
  }
  (void)nR1;
}

__global__ void __launch_bounds__(TT) k_tail(TailP P){
  __shared__ float sv[TT], sq[TT], la[128], lbv[128];
  __shared__ float buf[13824];   // 55.3 KB union of per-block halo tiles
  int* bar = P.bar;
  const int tile = blockIdx.x;

  // ---- block 2 (80x60, 16->32), tile 10x6, 80 tiles ----
  if (tile < 80) ph_A<80,60,10,6,16,32,true >(buf,sv,sq,P.mem1,P.p1w,P.p1b,P.c1w2,P.c1b2,P.lw2,P.lb2,P.stB2c1,P.stB2sk,3.f,3.f,tile);
  gridbar(bar, 1);
  if (tile < 80) ph_B<80,60,10,6,16,32>(buf,sv,sq,la,lbv,P.c2w2,P.c2b2,P.stB2c1,P.stB2c2,3.f,3.f,tile);
  gridbar(bar, 2);
  if (tile < 80) ph_C<80,60,10,6,16,32,true >(buf,sv,sq,la,lbv,P.stB2c2,P.stB2sk,P.p2w,P.p2b,P.out,P.g2p,tile);
  gridbar(bar, 3);
  // ---- block 3 (40x30, 32->64), tile 4x6, 50 tiles ----
  if (tile < 50) ph_A<40,30,4,6,32,64,false>(buf,sv,sq,P.g2p,nullptr,nullptr,P.c1w3,P.c1b3,P.lw3,P.lb3,P.stB3c1,P.stB3sk,6.f,6.f,tile);
  gridbar(bar, 4);
  if (tile < 50) ph_B<40,30,4,6,32,64>(buf,sv,sq,la,lbv,P.c2w3,P.c2b3,P.stB3c1,P.stB3c2,6.f,6.f,tile);
  gridbar(bar, 5);
  if (tile < 50) ph_C<40,30,4,6,32,64,true >(buf,sv,sq,la,lbv,P.stB3c2,P.stB3sk,P.p3w,P.p3b,P.out+153600,P.g3p,tile);
  gridbar(bar, 6);
  // ---- block 4 (20x15, 64->128), tile 2x3, 50 tiles, no pool ----
  if (tile < 50) ph_A<20,15,2,3,64,128,false>(buf,sv,sq,P.g3p,nullptr,nullptr,P.c1w4,P.c1b4,P.lw4,P.lb4,P.stB4c1,P.stB4sk,12.f,12.f,tile);
  gridbar(bar, 7);
  if (tile < 50) ph_B<20,15,2,3,64,128>(buf,sv,sq,la,lbv,P.c2w4,P.c2b4,P.stB4c1,P.stB4c2,12.f,12.f,tile);
  gridbar(bar, 8);
  if (tile < 50) ph_C<20,15,2,3,64,128,false>(buf,sv,sq,la,lbv,P.stB4c2,P.stB4sk,nullptr,nullptr,P.out+230400,nullptr,tile);
}

extern "C" void kernel_launch(void* const* d_in, const int* in_sizes, int n_in,
                              void* d_out, int out_size, void* d_ws, size_t ws_size,
                              hipStream_t stream){
  const float* x   = (const float*)d_in[0];
  const float* pos = (const float*)d_in[1];
  const int*   ei  = (const int*)d_in[2];
  const float* b1_c1w = (const float*)d_in[3];
  const float* b1_c1b = (const float*)d_in[4];
  const float* b1_c2w = (const float*)d_in[5];
  const float* b1_c2b = (const float*)d_in[6];
  const float* b1_lw  = (const float*)d_in[7];
  const float* b2_c1w = (const float*)d_in[9];
  const float* b2_c1b = (const float*)d_in[10];
  const float* b2_c2w = (const float*)d_in[11];
  const float* b2_c2b = (const float*)d_in[12];
  const float* b2_lw  = (const float*)d_in[13];
  const float* b2_lb  = (const float*)d_in[14];
  const float* b3_c1w = (const float*)d_in[15];
  const float* b3_c1b = (const float*)d_in[16];
  const float* b3_c2w = (const float*)d_in[17];
  const float* b3_c2b = (const float*)d_in[18];
  const float* b3_lw  = (const float*)d_in[19];
  const float* b3_lb  = (const float*)d_in[20];
  const float* b4_c1w = (const float*)d_in[21];
  const float* b4_c1b = (const float*)d_in[22];
  const float* b4_c2w = (const float*)d_in[23];
  const float* b4_c2b = (const float*)d_in[24];
  const float* b4_lw  = (const float*)d_in[25];
  const float* b4_lb  = (const float*)d_in[26];
  const float* p1w = (const float*)d_in[27];
  const float* p1b = (const float*)d_in[28];
  const float* p2w = (const float*)d_in[29];
  const float* p2b = (const float*)d_in[30];
  const float* p3w = (const float*)d_in[31];
  const float* p3b = (const float*)d_in[32];
  float* out = (float*)d_out;

  // ---- workspace carve ----
  float4* feat = (float4*)d_ws;       // NN float4 (3.2MB)
  float* A  = (float*)(feat + NN);    // NN*16 fp32; inter-block tail buffers ALIAS (A dead then)
  float* g2p  = A;                    // 1200*32 — alias, A dead after k_aggB
  float* g3p  = A + 38400;            // 300*64
  float* H  = A + NN*16;              // NN*16
  // Z region (single memset): bucket counters, barrier flags, stats, mem1
  int* bktCnt  = (int*)(H + NN*16);   // 256
  int* bktBase = bktCnt + 256;        // 257
  int* bktCur  = bktBase + 257;       // ends 769, pad to 1024
  int* bar     = bktCnt + 1024;       // flags: 80 x stride-32 + gen at [2560]; pad to 2624
  float* STz   = (float*)(bktCnt + 1024 + 2624);
  float* xstats = STz;                // 2
  float* st1    = STz + 16;
  float* st2    = STz + 64;
  float* stB2sk = STz + 128;
  float* stB2c1 = STz + 192;
  float* stB2c2 = STz + 256;
  float* stB3sk = STz + 320;
  float* stB3c1 = STz + 448;
  float* stB3c2 = STz + 576;
  float* stB4sk = STz + 704;
  float* stB4c1 = STz + 960;
  float* stB4c2 = STz + 1216;         // ..1471, pad to 1536
  float* mem1   = STz + 1536;         // 76800
  const size_t ZBYTES = (size_t)(1024 + 2624 + 1536 + 76800) * 4;
  int* pairs  = (int*)(mem1 + 76800); // NE ints (lives through aggA+aggB; no alias with A)

  hipMemsetAsync(bktCnt, 0, ZBYTES, stream);

  const int B = 256;
  // CSR bucket build (fused with feat/xstats prep); no within-bucket scatter pass
  k_cnt_prep<<<(NE+4095)/4096, 256, 0, stream>>>(ei, bktCnt, x, pos, feat, xstats);
  k_bktscan <<<1, 256, 0, stream>>>(bktCnt, bktBase, bktCur);
  k_part1   <<<(NE+16383)/16384, 1024, 0, stream>>>(ei, bktCur, pairs);

  // Block 1: bucket-resident LDS max-scatter convs, stats fused into epilogues
  k_aggA    <<<196, 1024, 0, stream>>>(pairs, bktBase, feat, pos, b1_c1w, b1_c1b, H, st1);
  k_prep2   <<<(NN*4+B-1)/B, B, 0, stream>>>(H, st1, pos, b1_c2w, (float4*)A);
  k_aggB    <<<196, 1024, 0, stream>>>(pairs, bktBase, (const float4*)A, pos, b1_c2w+256, b1_c2b, H, st2);
  k_comb_pool<<<(NN*4+B-1)/B, B, 0, stream>>>(H, x, pos, b1_lw, st2, xstats, mem1);

  // Fused tail: halo-tiled LDS-resident blocks 2-4, flag-array barrier, 1024 threads/WG
  TailP P;
  P.mem1 = mem1;
  P.p1w = p1w; P.p1b = p1b; P.p2w = p2w; P.p2b = p2b; P.p3w = p3w; P.p3b = p3b;
  P.c1w2 = b2_c1w; P.c1b2 = b2_c1b; P.c2w2 = b2_c2w; P.c2b2 = b2_c2b; P.lw2 = b2_lw; P.lb2 = b2_lb;
  P.c1w3 = b3_c1w; P.c1b3 = b3_c1b; P.c2w3 = b3_c2w; P.c2b3 = b3_c2b; P.lw3 = b3_lw; P.lb3 = b3_lb;
  P.c1w4 = b4_c1w; P.c1b4 = b4_c1b; P.c2w4 = b4_c2w; P.c2b4 = b4_c2b; P.lw4 = b4_lw; P.lb4 = b4_lb;
  P.g2p = g2p; P.g3p = g3p;
  P.stB2sk = stB2sk; P.stB2c1 = stB2c1; P.stB2c2 = stB2c2;
  P.stB3sk = stB3sk; P.stB3c1 = stB3c1; P.stB3c2 = stB3c2;
  P.stB4sk = stB4sk; P.stB4c1 = stB4c1; P.stB4c2 = stB4c2;
  P.out = out; P.bar = bar;
  k_tail<<<NWG, TT, 0, stream>>>(P);
}

// Round 5
// 430.181 us; speedup vs baseline: 1.5435x; 1.1242x over previous
//
#include <hip/hip_runtime.h>

#define NN 200000
#define NE 3200000
#define NWG 80
#define TT 1024
static constexpr float EPSV = 1e-5f;

// ---------------- CSR build: bucket sort (2 passes, no within-bucket scatter) ----------------
__global__ void k_cnt_prep(const int* __restrict__ ei, int* __restrict__ bktCnt,
                           const float* __restrict__ x, const float* __restrict__ pos,
                           float4* __restrict__ feat, float* __restrict__ xstats){
  __shared__ int cnt[256];
  __shared__ float sv[256], sq[256];
  int t = threadIdx.x;
  cnt[t] = 0;
  int i = blockIdx.x*256 + t;
  float xf = 0.f;
  if (i < NN){
    xf = x[i];
    feat[i] = make_float4(xf, pos[3*i], pos[3*i+1], 0.f);
  }
  sv[t] = (i < NN) ? xf : 0.f;
  sq[t] = sv[t]*sv[t];
  __syncthreads();
  int tile = blockIdx.x*4096;
  #pragma unroll
  for (int k = 0; k < 16; ++k){
    int e = tile + k*256 + t;
    if (e < NE) atomicAdd(&cnt[ei[NE+e]>>10], 1);
  }
  for (int o = 128; o > 0; o >>= 1){
    __syncthreads();
    if (t < o){ sv[t]+=sv[t+o]; sq[t]+=sq[t+o]; }
  }
  __syncthreads();
  if (t == 0){ atomicAdd(&xstats[0], sv[0]); atomicAdd(&xstats[1], sq[0]); }
  if (cnt[t]) atomicAdd(&bktCnt[t], cnt[t]);
}

__global__ void k_bktscan(const int* __restrict__ bktCnt, int* __restrict__ bktBase,
                          int* __restrict__ bktCur){
  __shared__ int s[256];
  int t = threadIdx.x;
  int v = bktCnt[t];
  s[t] = v; __syncthreads();
  for (int o = 1; o < 256; o <<= 1){
    int xv = (t >= o) ? s[t-o] : 0;
    __syncthreads(); s[t] += xv; __syncthreads();
  }
  int excl = s[t] - v;
  bktBase[t] = excl;
  bktCur[t]  = excl;
  if (t == 0){ bktBase[256] = NE; }
}

__global__ void k_part1(const int* __restrict__ ei, int* __restrict__ bktCur,
                        int* __restrict__ pairs){
  __shared__ int cnt[256]; __shared__ int base[256]; __shared__ int rank[256];
  int t = threadIdx.x;   // 1024 threads
  if (t < 256) cnt[t] = 0;
  __syncthreads();
  int tile = blockIdx.x*16384;
  #pragma unroll
  for (int k = 0; k < 16; ++k){
    int e = tile + k*1024 + t;
    if (e < NE) atomicAdd(&cnt[ei[NE+e]>>10], 1);
  }
  __syncthreads();
  if (t < 256){
    base[t] = cnt[t] ? atomicAdd(&bktCur[t], cnt[t]) : 0;
    rank[t] = 0;
  }
  __syncthreads();
  #pragma unroll
  for (int k = 0; k < 16; ++k){
    int e = tile + k*1024 + t;
    if (e < NE){
      int d = ei[NE+e], s = ei[e];
      int b = d >> 10;
      int r = atomicAdd(&rank[b], 1);
      pairs[base[b] + r] = (s<<10) | (d & 1023);
    }
  }
}

// ---------------- order-preserving float<->uint for atomicMax ----------------
__device__ __forceinline__ unsigned fenc(float f){
  unsigned u = __float_as_uint(f);
  return (u >> 31) ? ~u : (u | 0x80000000u);
}
__device__ __forceinline__ float fdec(unsigned k){
  unsigned u = (k >> 31) ? (k ^ 0x80000000u) : ~k;
  return __uint_as_float(u);
}
#define ENC_NI 0x007FFFFFu   /* fenc(-inf) */

// Bank-swizzled accumulator slot: group of dst d, channel c.
// bank = 16*(d&1) + ((c + (d>>1)) & 15): bit0 and bits1..4 of d are independent,
// so random d across a wave spreads all 32 banks (~2 lanes/bank = free).
__device__ __forceinline__ int aslot(int d, int c){
  return (d << 4) | ((c + (d >> 1)) & 15);
}

// ---------------- Block 1 conv1: bucket-resident LDS max-scatter, fused stats ----------------
__global__ void __launch_bounds__(1024) k_aggA(const int* __restrict__ pairs, const int* __restrict__ bktBase,
    const float4* __restrict__ feat, const float* __restrict__ pos,
    const float* __restrict__ w48, const float* __restrict__ bias,
    float* __restrict__ H, float* __restrict__ st){
  __shared__ unsigned acc[16384];   // 1024 dst x 16 ch (swizzled), 64KB
  const int b = blockIdx.x, t = threadIdx.x;
  for (int i = t; i < 16384; i += 1024) acc[i] = ENC_NI;
  float w0[16], w1[16], w2[16];
  #pragma unroll
  for (int c = 0; c < 16; ++c){ w0[c]=w48[c]; w1[c]=w48[16+c]; w2[c]=w48[32+c]; }
  const int p0 = bktBase[b], p1 = bktBase[b+1];
  __syncthreads();
  for (int j = p0 + t; j < p1; j += 1024){
    int pr = pairs[j];
    float4 f = feat[pr >> 10];
    int d = pr & 1023;
    int gbase = d << 4;
    int rot = (d >> 1) & 15;
    #pragma unroll
    for (int c = 0; c < 16; ++c){
      float m = f.x*w0[c] + f.y*w1[c] + f.z*w2[c];
      atomicMax(&acc[gbase | ((c + rot) & 15)], fenc(m));
    }
  }
  __syncthreads();
  const int base = b << 10;
  const int width = min(1024, NN - base);
  const int c = t & 15;
  const float b_c = bias[c], w1c = w48[16+c], w2c = w48[32+c];
  float ls = 0.f, lq = 0.f;
  for (int i = t; i < width*16; i += 1024){
    int dl = i >> 4, d = base + dl;
    int rot = (dl >> 1) & 15;
    float o = 0.f;
    if (acc[(dl << 4) | rot] != ENC_NI){   // channel-0 slot
      float px = pos[3*d], py = pos[3*d+1];
      o = fdec(acc[(dl << 4) | ((c + rot) & 15)]) + b_c - (px*w1c + py*w2c);
    }
    H[base*16 + i] = o;
    ls += o; lq += o*o;
  }
  __syncthreads();
  float* sv = (float*)acc; float* sq = sv + 1024;
  sv[t] = ls; sq[t] = lq; __syncthreads();
  for (int o2 = 512; o2 >= 16; o2 >>= 1){ if (t < o2){ sv[t]+=sv[t+o2]; sq[t]+=sq[t+o2]; } __syncthreads(); }
  if (t < 16){ atomicAdd(&st[t], sv[t]); atomicAdd(&st[16+t], sq[t]); }
}

// ---------------- Block 1 conv2: same structure over precomputed A ----------------
__global__ void __launch_bounds__(1024) k_aggB(const int* __restrict__ pairs, const int* __restrict__ bktBase,
    const float4* __restrict__ A4, const float* __restrict__ pos,
    const float* __restrict__ wpos, const float* __restrict__ bias,
    float* __restrict__ H, float* __restrict__ st){
  __shared__ unsigned acc[16384];
  const int b = blockIdx.x, t = threadIdx.x;
  for (int i = t; i < 16384; i += 1024) acc[i] = ENC_NI;
  const int p0 = bktBase[b], p1 = bktBase[b+1];
  __syncthreads();
  for (int j = p0 + t; j < p1; j += 1024){
    int pr = pairs[j];
    int s = pr >> 10;
    int d = pr & 1023;
    int gbase = d << 4;
    int rot = (d >> 1) & 15;
    float4 a0 = A4[s*4+0], a1 = A4[s*4+1], a2 = A4[s*4+2], a3 = A4[s*4+3];
    float av[16] = {a0.x,a0.y,a0.z,a0.w, a1.x,a1.y,a1.z,a1.w,
                    a2.x,a2.y,a2.z,a2.w, a3.x,a3.y,a3.z,a3.w};
    #pragma unroll
    for (int c = 0; c < 16; ++c)
      atomicMax(&acc[gbase | ((c + rot) & 15)], fenc(av[c]));
  }
  __syncthreads();
  const int base = b << 10;
  const int width = min(1024, NN - base);
  const int c = t & 15;
  const float b_c = bias[c], w1c = wpos[c], w2c = wpos[16+c];
  float ls = 0.f, lq = 0.f;
  for (int i = t; i < width*16; i += 1024){
    int dl = i >> 4, d = base + dl;
    int rot = (dl >> 1) & 15;
    float o = 0.f;
    if (acc[(dl << 4) | rot] != ENC_NI){
      float px = pos[3*d], py = pos[3*d+1];
      o = fdec(acc[(dl << 4) | ((c + rot) & 15)]) + b_c - (px*w1c + py*w2c);
    }
    H[base*16 + i] = o;
    ls += o; lq += o*o;
  }
  __syncthreads();
  float* sv = (float*)acc; float* sq = sv + 1024;
  sv[t] = ls; sq[t] = lq; __syncthreads();
  for (int o2 = 512; o2 >= 16; o2 >>= 1){ if (t < o2){ sv[t]+=sv[t+o2]; sq[t]+=sq[t+o2]; } __syncthreads(); }
  if (t < 16){ atomicAdd(&st[t], sv[t]); atomicAdd(&st[16+t], sq[t]); }
}

__global__ void k_prep2(const float* __restrict__ Hraw, const float* __restrict__ st1,
                        const float* __restrict__ pos, const float* __restrict__ w,
                        float4* __restrict__ A4){
  int idx = blockIdx.x*blockDim.x + threadIdx.x;
  if (idx >= NN*4) return;
  int i = idx >> 2, cg = idx & 3;
  const float inv_n = 1.f/(float)NN;
  float acc0 = 0.f, acc1 = 0.f, acc2 = 0.f, acc3 = 0.f;
  #pragma unroll
  for (int k = 0; k < 16; ++k){
    float mk = st1[k]*inv_n;
    float vk = st1[16+k]*inv_n - mk*mk;
    float ik = rsqrtf(vk + EPSV);
    float h = fmaxf((Hraw[i*16+k]-mk)*ik, 0.f);
    acc0 += h*w[k*16 + cg*4 + 0];
    acc1 += h*w[k*16 + cg*4 + 1];
    acc2 += h*w[k*16 + cg*4 + 2];
    acc3 += h*w[k*16 + cg*4 + 3];
  }
  float px = pos[3*i], py = pos[3*i+1];
  int c0 = cg*4;
  acc0 += px*w[256+c0+0] + py*w[272+c0+0];
  acc1 += px*w[256+c0+1] + py*w[272+c0+1];
  acc2 += px*w[256+c0+2] + py*w[272+c0+2];
  acc3 += px*w[256+c0+3] + py*w[272+c0+3];
  A4[idx] = make_float4(acc0, acc1, acc2, acc3);
}

__global__ void k_comb_pool(const float* __restrict__ H, const float* __restrict__ x,
                            const float* __restrict__ pos, const float* __restrict__ lw,
                            const float* __restrict__ st2, const float* __restrict__ xstats,
                            float* __restrict__ mem){
  int idx = blockIdx.x*blockDim.x + threadIdx.x;
  if (idx >= NN*4) return;
  int i = idx >> 2, cg = idx & 3;
  const float inv_n = 1.f/(float)NN;
  float mx = xstats[0]*inv_n, vx = xstats[1]*inv_n - mx*mx;
  float xc = x[i] - mx;
  float px = pos[3*i], py = pos[3*i+1];
  int cx = (int)(px * 80.f / 240.f); cx = min(max(cx,0),79);
  int cy = (int)(py * 60.f / 180.f); cy = min(max(cy,0),59);
  float* mrow = &mem[(cy*80+cx)*16 + cg*4];
  #pragma unroll
  for (int k = 0; k < 4; ++k){
    int c = cg*4 + k;
    float m2 = st2[c]*inv_n, v2 = st2[16+c]*inv_n - m2*m2;
    float i2 = rsqrtf(v2 + EPSV);
    float a = lw[c];
    float sc = a * rsqrtf(a*a*vx + EPSV);
    float v = (H[i*16+c]-m2)*i2 + xc*sc;
    v = fmaxf(v, 0.f);
    atomicAdd(&mrow[k], v);
  }
}

// ---------------- Fused tail: halo-tiled, LDS-resident, flag-array barrier ----------------
__device__ __forceinline__ void stwt(float* p, float v){
  __hip_atomic_store(p, v, __ATOMIC_RELAXED, __HIP_MEMORY_SCOPE_AGENT);
}
__device__ __forceinline__ float ldwt(const float* p){
  return __hip_atomic_load(p, __ATOMIC_RELAXED, __HIP_MEMORY_SCOPE_AGENT);
}

// Flag-array barrier, monotonic generation (no reset round trip).
// bar layout (ints, zeroed at launch): flag[wg] at bar[32*wg] (own cacheline); gen at bar[2560].
__device__ __forceinline__ void gridbar(int* bar, int target){
  __syncthreads();   // compiler drains each wave's vm/lgkm before s_barrier
  const int t = threadIdx.x;
  if (blockIdx.x == 0){
    if (t >= 1 && t < NWG){
      while (__hip_atomic_load(bar + 32*t, __ATOMIC_RELAXED, __HIP_MEMORY_SCOPE_AGENT) < target)
        __builtin_amdgcn_s_sleep(1);
    }
    __syncthreads();
    if (t == 0)
      __hip_atomic_store(bar + 2560, target, __ATOMIC_RELAXED, __HIP_MEMORY_SCOPE_AGENT);
  } else {
    if (t == 0){
      __atomic_signal_fence(__ATOMIC_SEQ_CST);
      __builtin_amdgcn_s_waitcnt(0);   // this wave's stores durable before arrival flag
      __atomic_signal_fence(__ATOMIC_SEQ_CST);
      __hip_atomic_store(bar + 32*blockIdx.x, target, __ATOMIC_RELAXED, __HIP_MEMORY_SCOPE_AGENT);
      while (__hip_atomic_load(bar + 2560, __ATOMIC_RELAXED, __HIP_MEMORY_SCOPE_AGENT) < target)
        __builtin_amdgcn_s_sleep(2);
    }
    __syncthreads();
  }
}

struct TailP {
  const float *mem1;
  const float *p1w,*p1b,*p2w,*p2b,*p3w,*p3b;
  const float *c1w2,*c1b2,*c2w2,*c2b2,*lw2,*lb2;
  const float *c1w3,*c1b3,*c2w3,*c2b3,*lw3,*lb3;
  const float *c1w4,*c1b4,*c2w4,*c2b4,*lw4,*lb4;
  float *g2p,*g3p;
  float *stB2sk,*stB2c1,*stB2c2,*stB3sk,*stB3c1,*stB3c2,*stB4sk,*stB4c1,*stB4c2;
  float *out;
  int *bar;
};

// Phase A: G on T+2 halo (poollin for block2, ldwt(Gp) else); S = G@c1w on T+2;
//          SK = G@lw+lb on T (+stats); H1 = gridagg(S) on T+1 (+stats over owned T).
template<int GW,int GH,int TW,int TH,int K,int C,bool FIRST>
__device__ __forceinline__ void ph_A(float* buf, float* sv, float* sq,
    const float* __restrict__ Gglob, const float* __restrict__ plw, const float* __restrict__ plb,
    const float* __restrict__ c1w, const float* __restrict__ c1b,
    const float* __restrict__ lw, const float* __restrict__ lb,
    float* stH1, float* stSK, float sx, float sy, int tile)
{
  constexpr int W2=TW+4, nR2=W2*(TH+4);
  constexpr int W1=TW+2, nR1=W1*(TH+2);
  constexpr int nT=TW*TH, NTX=GW/TW;
  const int tx0=(tile%NTX)*TW, ty0=(tile/NTX)*TH;
  float* Gl=buf; float* Sl=Gl+nR2*K; float* H1l=Sl+nR2*C; float* SKl=H1l+nR1*C;
  const int t=threadIdx.x;
  if constexpr (FIRST){
    for (int e=t; e<nR2*K; e+=TT){
      int cell=e/K, k=e-cell*K;
      int gx=tx0-2+cell%W2, gy=ty0-2+cell/W2;
      Sl[e] = (gx>=0&&gx<GW&&gy>=0&&gy<GH) ? Gglob[(gy*GW+gx)*K+k] : 0.f;
    }
    __syncthreads();
    for (int e=t; e<nR2*K; e+=TT){
      int cell=e/K, c=e-cell*K;
      float acc=plb[c];
      #pragma unroll
      for (int k=0;k<K;++k) acc += Sl[cell*K+k]*plw[k*K+c];
      Gl[e] = (acc>1.f)?acc:0.f;
    }
  } else {
    for (int e=t; e<nR2*K; e+=TT){
      int cell=e/K, k=e-cell*K;
      int gx=tx0-2+cell%W2, gy=ty0-2+cell/W2;
      Gl[e] = (gx>=0&&gx<GW&&gy>=0&&gy<GH) ? ldwt(&Gglob[(gy*GW+gx)*K+k]) : 0.f;
    }
  }
  __syncthreads();
  // S on T+2 (out-of-grid cells compute from zeros; never read)
  for (int e=t; e<nR2*C; e+=TT){
    int cell=e/C, c=e-cell*C;
    float acc=0.f;
    #pragma unroll 8
    for (int k=0;k<K;++k) acc += Gl[cell*K+k]*c1w[k*C+c];
    Sl[e]=acc;
  }
  // SK on owned T + stats
  float ls=0.f,lq=0.f;
  for (int e=t; e<nT*C; e+=TT){
    int cell=e/C, c=e-cell*C;
    int lx=cell%TW, ly=cell/TW;
    int g2=(ly+2)*W2+(lx+2);
    float acc=lb[c];
    #pragma unroll 8
    for (int k=0;k<K;++k) acc += Gl[g2*K+k]*lw[k*C+c];
    SKl[e]=acc; ls+=acc; lq+=acc*acc;
  }
  __syncthreads();
  sv[t]=ls; sq[t]=lq; __syncthreads();
  for (int o=TT/2;o>=C;o>>=1){ if(t<o){sv[t]+=sv[t+o];sq[t]+=sq[t+o];} __syncthreads(); }
  if (t<C){ atomicAdd(&stSK[t],sv[t]); atomicAdd(&stSK[C+t],sq[t]); }
  __syncthreads();
  // H1 = gridagg(S) on T+1; stats over owned T only
  ls=0.f; lq=0.f;
  const float NI=-__builtin_inff();
  for (int e=t; e<nR1*C; e+=TT){
    int cell=e/C, c=e-cell*C;
    int lx=cell%W1, ly=cell/W1;
    int gx=tx0-1+lx, gy=ty0-1+ly;
    if (gx<0||gx>=GW||gy<0||gy>=GH) continue;
    float wx=c1w[K*C+c], wy=c1w[(K+1)*C+c];
    float m=NI;
    #pragma unroll
    for (int oy=-1;oy<=1;++oy){
      int ny=gy+oy; if (ny<0||ny>=GH) continue;
      #pragma unroll
      for (int ox=-1;ox<=1;++ox){
        int nx=gx+ox; if (nx<0||nx>=GW) continue;
        int l2=(ly+1+oy)*W2+(lx+1+ox);
        m=fmaxf(m, Sl[l2*C+c]+(ox*sx)*wx+(oy*sy)*wy);
      }
    }
    float val=m+c1b[c];
    H1l[e]=val;
    if (gx>=tx0&&gx<tx0+TW&&gy>=ty0&&gy<ty0+TH){ ls+=val; lq+=val*val; }
  }
  __syncthreads();
  sv[t]=ls; sq[t]=lq; __syncthreads();
  for (int o=TT/2;o>=C;o>>=1){ if(t<o){sv[t]+=sv[t+o];sq[t]+=sq[t+o];} __syncthreads(); }
  if (t<C){ atomicAdd(&stH1[t],sv[t]); atomicAdd(&stH1[C+t],sq[t]); }
}

// Phase B: normalize H1 (global stats) on T+1; S2 = relu(BN(H1))@c2w on T+1;
//          H2 = gridagg(S2) on T (+stats).
template<int GW,int GH,int TW,int TH,int K,int C>
__device__ __forceinline__ void ph_B(float* buf, float* sv, float* sq, float* la, float* lbv,
    const float* __restrict__ c2w, const float* __restrict__ c2b,
    const float* stH1, float* stH2, float sx, float sy, int tile)
{
  constexpr int W2=TW+4, nR2=W2*(TH+4);
  constexpr int W1=TW+2, nR1=W1*(TH+2);
  constexpr int nT=TW*TH, NTX=GW/TW;
  const int tx0=(tile%NTX)*TW, ty0=(tile/NTX)*TH;
  float* Gl=buf; float* Sl=Gl+nR2*K; float* H1l=Sl+nR2*C; float* SKl=H1l+nR1*C; float* H2l=SKl+nT*C;
  const int t=threadIdx.x;
  const float invn=1.f/(float)(GW*GH);
  if (t<C){
    float mk=ldwt(&stH1[t])*invn;
    float vk=ldwt(&stH1[C+t])*invn - mk*mk;
    float ik=rsqrtf(vk+EPSV);
    la[t]=ik; lbv[t]=-mk*ik;
  }
  __syncthreads();
  for (int e=t;e<nR1*C;e+=TT){
    int cell=e/C,c=e-cell*C;
    int gx=tx0-1+cell%W1, gy=ty0-1+cell/W1;
    if (gx<0||gx>=GW||gy<0||gy>=GH) continue;
    H1l[e]=fmaxf(H1l[e]*la[c]+lbv[c],0.f);
  }
  __syncthreads();
  // S2 on T+1 (region1 layout, reusing S buffer)
  for (int e=t;e<nR1*C;e+=TT){
    int cell=e/C,c=e-cell*C;
    int gx=tx0-1+cell%W1, gy=ty0-1+cell/W1;
    if (gx<0||gx>=GW||gy<0||gy>=GH) continue;
    float acc=0.f;
    #pragma unroll 8
    for (int k=0;k<C;++k) acc += H1l[cell*C+k]*c2w[k*C+c];
    Sl[e]=acc;
  }
  __syncthreads();
  float ls=0.f,lq=0.f;
  const float NI=-__builtin_inff();
  for (int e=t;e<nT*C;e+=TT){
    int cell=e/C,c=e-cell*C;
    int lx=cell%TW, ly=cell/TW;
    int gx=tx0+lx, gy=ty0+ly;
    float wx=c2w[C*C+c], wy=c2w[(C+1)*C+c];
    float m=NI;
    #pragma unroll
    for (int oy=-1;oy<=1;++oy){
      int ny=gy+oy; if (ny<0||ny>=GH) continue;
      #pragma unroll
      for (int ox=-1;ox<=1;++ox){
        int nx=gx+ox; if (nx<0||nx>=GW) continue;
        int l1=(ly+1+oy)*W1+(lx+1+ox);
        m=fmaxf(m, Sl[l1*C+c]+(ox*sx)*wx+(oy*sy)*wy);
      }
    }
    float val=m+c2b[c];
    H2l[e]=val; ls+=val; lq+=val*val;
  }
  __syncthreads();
  sv[t]=ls; sq[t]=lq; __syncthreads();
  for (int o=TT/2;o>=C;o>>=1){ if(t<o){sv[t]+=sv[t+o];sq[t]+=sq[t+o];} __syncthreads(); }
  if (t<C){ atomicAdd(&stH2[t],sv[t]); atomicAdd(&stH2[C+t],sq[t]); }
}

// Phase C: out = relu(BN(H2)+BN(SK)) on T -> global; 2x2 pool + poollin -> Gp.
template<int GW,int GH,int TW,int TH,int K,int C,bool POOL>
__device__ __forceinline__ void ph_C(float* buf, float* asv, float* asq, float* la, float* lbv,
    const float* stH2, const float* stSK,
    const float* __restrict__ pw, const float* __restrict__ pb,
    float* __restrict__ outg, float* __restrict__ Gpg, int tile)
{
  constexpr int W2=TW+4, nR2=W2*(TH+4);
  constexpr int W1=TW+2, nR1=W1*(TH+2);
  constexpr int nT=TW*TH, NTX=GW/TW;
  const int tx0=(tile%NTX)*TW, ty0=(tile/NTX)*TH;
  float* Gl=buf; float* Sl=Gl+nR2*K; float* H1l=Sl+nR2*C; float* SKl=H1l+nR1*C; float* H2l=SKl+nT*C;
  const int t=threadIdx.x;
  const float invn=1.f/(float)(GW*GH);
  if (t<C){
    float m2=ldwt(&stH2[t])*invn, v2=ldwt(&stH2[C+t])*invn-m2*m2;
    float i2=rsqrtf(v2+EPSV);
    la[t]=i2; lbv[t]=-m2*i2;
    float ms=ldwt(&stSK[t])*invn, vs=ldwt(&stSK[C+t])*invn-ms*ms;
    float is_=rsqrtf(vs+EPSV);
    asv[t]=is_; asq[t]=-ms*is_;
  }
  __syncthreads();
  float* OUTl=Sl;   // S2 dead; reuse as combined-output tile
  for (int e=t;e<nT*C;e+=TT){
    int cell=e/C,c=e-cell*C;
    int lx=cell%TW, ly=cell/TW;
    int gx=tx0+lx, gy=ty0+ly;
    float v=(H2l[e]*la[c]+lbv[c])+(SKl[e]*asv[c]+asq[c]);
    v=fmaxf(v,0.f);
    outg[(gy*GW+gx)*C+c]=v;   // plain store: flushed at kernel end
    OUTl[e]=v;
  }
  if constexpr (POOL){
    __syncthreads();
    constexpr int PTW=TW/2, PTH=TH/2, nP=PTW*PTH, PGW=GW/2;
    float* Ml=H1l;  // H1 dead; reuse as pooled sums
    for (int e=t;e<nP*C;e+=TT){
      int pc=e/C,c=e-pc*C;
      int plx=pc%PTW, ply=pc/PTW;
      float s=0.f;
      #pragma unroll
      for (int dy=0;dy<2;++dy)
        #pragma unroll
        for (int dx=0;dx<2;++dx)
          s += OUTl[((2*ply+dy)*TW+(2*plx+dx))*C+c];
      Ml[e]=s;
    }
    __syncthreads();
    for (int e=t;e<nP*C;e+=TT){
      int pc=e/C,c=e-pc*C;
      int plx=pc%PTW, ply=pc/PTW;
      float acc=pb[c];
      #pragma unroll 8
      for (int k=0;k<C;++k) acc += Ml[pc*C+k]*pw[k*C+c];
      int gpx=tx0/2+plx, gpy=ty0/2+ply;
      stwt(&Gpg[(gpy*PGW+gpx)*C+c], (acc>1.f)?acc:0.f);
    }
  }
  (void)nR1;
}

__global__ void __launch_bounds__(TT) k_tail(TailP P){
  __shared__ float sv[TT], sq[TT], la[128], lbv[128];
  __shared__ float buf[13824];   // 55.3 KB union of per-block halo tiles
  int* bar = P.bar;
  const int tile = blockIdx.x;

  // ---- block 2 (80x60, 16->32), tile 10x6, 80 tiles ----
  if (tile < 80) ph_A<80,60,10,6,16,32,true >(buf,sv,sq,P.mem1,P.p1w,P.p1b,P.c1w2,P.c1b2,P.lw2,P.lb2,P.stB2c1,P.stB2sk,3.f,3.f,tile);
  gridbar(bar, 1);
  if (tile < 80) ph_B<80,60,10,6,16,32>(buf,sv,sq,la,lbv,P.c2w2,P.c2b2,P.stB2c1,P.stB2c2,3.f,3.f,tile);
  gridbar(bar, 2);
  if (tile < 80) ph_C<80,60,10,6,16,32,true >(buf,sv,sq,la,lbv,P.stB2c2,P.stB2sk,P.p2w,P.p2b,P.out,P.g2p,tile);
  gridbar(bar, 3);
  // ---- block 3 (40x30, 32->64), tile 4x6, 50 tiles ----
  if (tile < 50) ph_A<40,30,4,6,32,64,false>(buf,sv,sq,P.g2p,nullptr,nullptr,P.c1w3,P.c1b3,P.lw3,P.lb3,P.stB3c1,P.stB3sk,6.f,6.f,tile);
  gridbar(bar, 4);
  if (tile < 50) ph_B<40,30,4,6,32,64>(buf,sv,sq,la,lbv,P.c2w3,P.c2b3,P.stB3c1,P.stB3c2,6.f,6.f,tile);
  gridbar(bar, 5);
  if (tile < 50) ph_C<40,30,4,6,32,64,true >(buf,sv,sq,la,lbv,P.stB3c2,P.stB3sk,P.p3w,P.p3b,P.out+153600,P.g3p,tile);
  gridbar(bar, 6);
  // ---- block 4 (20x15, 64->128), tile 2x3, 50 tiles, no pool ----
  if (tile < 50) ph_A<20,15,2,3,64,128,false>(buf,sv,sq,P.g3p,nullptr,nullptr,P.c1w4,P.c1b4,P.lw4,P.lb4,P.stB4c1,P.stB4sk,12.f,12.f,tile);
  gridbar(bar, 7);
  if (tile < 50) ph_B<20,15,2,3,64,128>(buf,sv,sq,la,lbv,P.c2w4,P.c2b4,P.stB4c1,P.stB4c2,12.f,12.f,tile);
  gridbar(bar, 8);
  if (tile < 50) ph_C<20,15,2,3,64,128,false>(buf,sv,sq,la,lbv,P.stB4c2,P.stB4sk,nullptr,nullptr,P.out+230400,nullptr,tile);
}

extern "C" void kernel_launch(void* const* d_in, const int* in_sizes, int n_in,
                              void* d_out, int out_size, void* d_ws, size_t ws_size,
                              hipStream_t stream){
  const float* x   = (const float*)d_in[0];
  const float* pos = (const float*)d_in[1];
  const int*   ei  = (const int*)d_in[2];
  const float* b1_c1w = (const float*)d_in[3];
  const float* b1_c1b = (const float*)d_in[4];
  const float* b1_c2w = (const float*)d_in[5];
  const float* b1_c2b = (const float*)d_in[6];
  const float* b1_lw  = (const float*)d_in[7];
  const float* b2_c1w = (const float*)d_in[9];
  const float* b2_c1b = (const float*)d_in[10];
  const float* b2_c2w = (const float*)d_in[11];
  const float* b2_c2b = (const float*)d_in[12];
  const float* b2_lw  = (const float*)d_in[13];
  const float* b2_lb  = (const float*)d_in[14];
  const float* b3_c1w = (const float*)d_in[15];
  const float* b3_c1b = (const float*)d_in[16];
  const float* b3_c2w = (const float*)d_in[17];
  const float* b3_c2b = (const float*)d_in[18];
  const float* b3_lw  = (const float*)d_in[19];
  const float* b3_lb  = (const float*)d_in[20];
  const float* b4_c1w = (const float*)d_in[21];
  const float* b4_c1b = (const float*)d_in[22];
  const float* b4_c2w = (const float*)d_in[23];
  const float* b4_c2b = (const float*)d_in[24];
  const float* b4_lw  = (const float*)d_in[25];
  const float* b4_lb  = (const float*)d_in[26];
  const float* p1w = (const float*)d_in[27];
  const float* p1b = (const float*)d_in[28];
  const float* p2w = (const float*)d_in[29];
  const float* p2b = (const float*)d_in[30];
  const float* p3w = (const float*)d_in[31];
  const float* p3b = (const float*)d_in[32];
  float* out = (float*)d_out;

  // ---- workspace carve ----
  float4* feat = (float4*)d_ws;       // NN float4 (3.2MB)
  float* A  = (float*)(feat + NN);    // NN*16 fp32; inter-block tail buffers ALIAS (A dead then)
  float* g2p  = A;                    // 1200*32 — alias, A dead after k_aggB
  float* g3p  = A + 38400;            // 300*64
  float* H  = A + NN*16;              // NN*16
  // Z region (single memset): bucket counters, barrier flags, stats, mem1
  int* bktCnt  = (int*)(H + NN*16);   // 256
  int* bktBase = bktCnt + 256;        // 257
  int* bktCur  = bktBase + 257;       // ends 769, pad to 1024
  int* bar     = bktCnt + 1024;       // flags: 80 x stride-32 + gen at [2560]; pad to 2624
  float* STz   = (float*)(bktCnt + 1024 + 2624);
  float* xstats = STz;                // 2
  float* st1    = STz + 16;
  float* st2    = STz + 64;
  float* stB2sk = STz + 128;
  float* stB2c1 = STz + 192;
  float* stB2c2 = STz + 256;
  float* stB3sk = STz + 320;
  float* stB3c1 = STz + 448;
  float* stB3c2 = STz + 576;
  float* stB4sk = STz + 704;
  float* stB4c1 = STz + 960;
  float* stB4c2 = STz + 1216;         // ..1471, pad to 1536
  float* mem1   = STz + 1536;         // 76800
  const size_t ZBYTES = (size_t)(1024 + 2624 + 1536 + 76800) * 4;
  int* pairs  = (int*)(mem1 + 76800); // NE ints (lives through aggA+aggB; no alias with A)

  hipMemsetAsync(bktCnt, 0, ZBYTES, stream);

  const int B = 256;
  // CSR bucket build (fused with feat/xstats prep); no within-bucket scatter pass
  k_cnt_prep<<<(NE+4095)/4096, 256, 0, stream>>>(ei, bktCnt, x, pos, feat, xstats);
  k_bktscan <<<1, 256, 0, stream>>>(bktCnt, bktBase, bktCur);
  k_part1   <<<(NE+16383)/16384, 1024, 0, stream>>>(ei, bktCur, pairs);

  // Block 1: bucket-resident LDS max-scatter convs (bank-swizzled acc), fused stats
  k_aggA    <<<196, 1024, 0, stream>>>(pairs, bktBase, feat, pos, b1_c1w, b1_c1b, H, st1);
  k_prep2   <<<(NN*4+B-1)/B, B, 0, stream>>>(H, st1, pos, b1_c2w, (float4*)A);
  k_aggB    <<<196, 1024, 0, stream>>>(pairs, bktBase, (const float4*)A, pos, b1_c2w+256, b1_c2b, H, st2);
  k_comb_pool<<<(NN*4+B-1)/B, B, 0, stream>>>(H, x, pos, b1_lw, st2, xstats, mem1);

  // Fused tail: halo-tiled LDS-resident blocks 2-4, flag-array barrier, 1024 threads/WG
  TailP P;
  P.mem1 = mem1;
  P.p1w = p1w; P.p1b = p1b; P.p2w = p2w; P.p2b = p2b; P.p3w = p3w; P.p3b = p3b;
  P.c1w2 = b2_c1w; P.c1b2 = b2_c1b; P.c2w2 = b2_c2w; P.c2b2 = b2_c2b; P.lw2 = b2_lw; P.lb2 = b2_lb;
  P.c1w3 = b3_c1w; P.c1b3 = b3_c1b; P.c2w3 = b3_c2w; P.c2b3 = b3_c2b; P.lw3 = b3_lw; P.lb3 = b3_lb;
  P.c1w4 = b4_c1w; P.c1b4 = b4_c1b; P.c2w4 = b4_c2w; P.c2b4 = b4_c2b; P.lw4 = b4_lw; P.lb4 = b4_lb;
  P.g2p = g2p; P.g3p = g3p;
  P.stB2sk = stB2sk; P.stB2c1 = stB2c1; P.stB2c2 = stB2c2;
  P.stB3sk = stB3sk; P.stB3c1 = stB3c1; P.stB3c2 = stB3c2;
  P.stB4sk = stB4sk; P.stB4c1 = stB4c1; P.stB4c2 = stB4c2;
  P.out = out; P.bar = bar;
  k_tail<<<NWG, TT, 0, stream>>>(P);
}